// Round 7
// baseline (3142.831 us; speedup 1.0000x reference)
//
#include <hip/hip_runtime.h>
#include <stdint.h>

// ---------------------------------------------------------------------------
// Conv-SNN, 100 steps, B=64, BETA=0.
// Round 7: convs in f32 (v_pk_fma_f32) with rigorous error interval;
// outputs within eps of a spike threshold are recomputed exactly in f64 by
// a fixup kernel that patches the A/B bits. Everything downstream of the
// bits (scans, FC, LIF3) unchanged from round 6 (absmax 0.0 lineage).
// ---------------------------------------------------------------------------

#define NSTEPS 100
#define NB 64
#define CAP_FIX 1048576u

typedef float f32x2 __attribute__((ext_vector_type(2)));

__device__ __forceinline__ uint32_t rotl32(uint32_t v, uint32_t r) {
  return (v << r) | (v >> (32u - r));
}

__device__ __forceinline__ void threefry2x32(uint32_t k0, uint32_t k1,
                                             uint32_t& x0, uint32_t& x1) {
  uint32_t k2 = k0 ^ k1 ^ 0x1BD11BDAu;
  x0 += k0; x1 += k1;
#define TF_R(r) { x0 += x1; x1 = rotl32(x1, r); x1 ^= x0; }
  TF_R(13u) TF_R(15u) TF_R(26u) TF_R(6u)
  x0 += k1; x1 += k2 + 1u;
  TF_R(17u) TF_R(29u) TF_R(16u) TF_R(24u)
  x0 += k2; x1 += k0 + 2u;
  TF_R(13u) TF_R(15u) TF_R(26u) TF_R(6u)
  x0 += k0; x1 += k1 + 3u;
  TF_R(17u) TF_R(29u) TF_R(16u) TF_R(24u)
  x0 += k1; x1 += k2 + 4u;
  TF_R(13u) TF_R(15u) TF_R(26u) TF_R(6u)
  x0 += k2; x1 += k0 + 5u;
#undef TF_R
}

__device__ __forceinline__ double fold_pool_w(const float* W, int base, int pos) {
  int iy = pos / 6, ix = pos % 6;
  double w = 0.0;
  for (int dy = 0; dy < 2; ++dy) {
    int ky = iy - dy; if (ky < 0 || ky > 4) continue;
    for (int dx = 0; dx < 2; ++dx) {
      int kx = ix - dx; if (kx < 0 || kx > 4) continue;
      w += (double)W[base + ky * 5 + kx];
    }
  }
  return w;
}

// Folded-pool weights, f64 masters + f32 copies.
// W1R/W1F: [og4][pos36][c3][oj8]   (oc = og*8+oj)
// W2R/W2F: [og4][c32][pos36][oj16] (oc = og*16+oj)
__global__ __launch_bounds__(256) void weff_all(const float* __restrict__ W_in,
                                                const float* __restrict__ W_h1,
                                                double* __restrict__ W1R,
                                                double* __restrict__ W2R,
                                                float* __restrict__ W1F,
                                                float* __restrict__ W2F) {
  int e = blockIdx.x * 256 + threadIdx.x;
  if (e < 3456) {
    int oj = e & 7, c = (e >> 3) % 3, pos = ((e >> 3) / 3) % 36, og = (e >> 3) / 108;
    int oc = og * 8 + oj;
    double w = fold_pool_w(W_in, (oc * 3 + c) * 25, pos);
    W1R[e] = w; W1F[e] = (float)w;
  } else if (e < 3456 + 73728) {
    int e2 = e - 3456;
    int oj = e2 & 15, pos = (e2 >> 4) % 36, c = ((e2 >> 4) / 36) % 32, og = e2 / 18432;
    int oc = og * 16 + oj;
    double w = fold_pool_w(W_h1, (oc * 32 + c) * 25, pos);
    W2R[e2] = w; W2F[e2] = (float)w;
  }
}

// EPS[0..31]: conv1 per-oc flag radius; EPS[32..95]: conv2 per-oc.
__global__ __launch_bounds__(128) void eps_kernel(const double* __restrict__ W1R,
                                                  const double* __restrict__ W2R,
                                                  float* __restrict__ EPS) {
  int oc = blockIdx.x * 128 + threadIdx.x;
  const double u24 = 5.9604644775390625e-08;
  if (oc < 32) {
    int og = oc >> 3, oj = oc & 7;
    double S = 0.0;
    for (int pos = 0; pos < 36; ++pos)
      for (int c = 0; c < 3; ++c) S += fabs(W1R[og * 864 + pos * 24 + c * 8 + oj]);
    EPS[oc] = (float)(S * (108.0 * u24 * 6.0) * 0.25);
  } else if (oc < 96) {
    int o = oc - 32, og = o >> 4, oj = o & 15;
    double S = 0.0;
    for (int c = 0; c < 32; ++c)
      for (int pos = 0; pos < 36; ++pos) S += fabs(W2R[og * 18432 + c * 576 + pos * 16 + oj]);
    EPS[oc] = (float)(S * (1152.0 * u24 * 6.0) * 0.25);
  }
}

// --- spike gen: per-pixel 3-bit channel codes [t,b,1024] bytes ------------
__global__ __launch_bounds__(256) void gen_spikes(const float* __restrict__ x,
                                                  unsigned char* __restrict__ spk0c) {
  int g = blockIdx.x * 256 + threadIdx.x;
  if (g >= NSTEPS * NB * 1024) return;
  int tb = g >> 10, pix = g & 1023;
  int b = tb & 63;
  unsigned code = 0;
  #pragma unroll
  for (int c = 0; c < 3; ++c) {
    uint32_t i = (uint32_t)((tb * 3 + c) * 1024 + pix);
    uint32_t x0 = 0u, x1 = i;
    threefry2x32(0u, 1u, x0, x1);
    uint32_t bits = x0 ^ x1;
    float u = __uint_as_float((bits >> 9) | 0x3f800000u) - 1.0f;
    float xv = x[(b * 3 + c) * 1024 + pix];
    code |= (u < 2.0f * xv) ? (1u << c) : 0u;
  }
  spk0c[g] = (unsigned char)code;
}

// --- conv1+pool f32, 4 t per thread, flat over (tq,b,p) -------------------
__global__ __launch_bounds__(256, 4) void conv1_f32(const unsigned char* __restrict__ spk0c,
                                                    const float* __restrict__ W1F,
                                                    const float* __restrict__ EPS,
                                                    unsigned char* __restrict__ A1,
                                                    unsigned char* __restrict__ B1,
                                                    uint32_t* __restrict__ cnt,
                                                    uint2* __restrict__ list1) {
  const int og  = blockIdx.y;
  const int tid = threadIdx.x;
  const int id0 = blockIdx.x * 256;
  const int id  = id0 + tid;
  const int tb0 = id0 / 196;
  __shared__ unsigned char sC[3][4][1024];

  #pragma unroll
  for (int k = 0; k < 3; ++k) {
    int idx = tid + k * 256;
    int fi = idx >> 6, lane = idx & 63;
    int seg = fi >> 2, tt = fi & 3;
    int tb = tb0 + seg; if (tb > 1599) tb = 1599;
    int b = tb & 63, tq = tb >> 6;
    ((uint4*)sC)[idx] =
        ((const uint4*)(spk0c + (size_t)((tq * 4 + tt) * NB + b) * 1024))[lane];
  }
  __syncthreads();

  const int tb  = id / 196;
  const int p   = id - tb * 196;
  const int seg = tb - tb0;
  const int b = tb & 63, tq = tb >> 6;
  const int oh = p / 14, ow = p - oh * 14;
  const unsigned char* base = &sC[seg][0][(2 * oh) * 32 + 2 * ow];
  const float* Wb = W1F + og * 864;

  f32x2 acc[16];
  #pragma unroll
  for (int i = 0; i < 16; ++i) acc[i] = (f32x2)(0.0f);

  #pragma unroll
  for (int iy = 0; iy < 6; ++iy) {
    #pragma unroll
    for (int ix = 0; ix < 6; ++ix) {
      const int pos = iy * 6 + ix, off = iy * 32 + ix;
      unsigned c0 = base[0 * 1024 + off];
      unsigned c1 = base[1 * 1024 + off];
      unsigned c2 = base[2 * 1024 + off];
      unsigned c3 = base[3 * 1024 + off];
      #pragma unroll
      for (int c = 0; c < 3; ++c) {
        float f0 = (float)((c0 >> c) & 1u), f1 = (float)((c1 >> c) & 1u);
        float f2 = (float)((c2 >> c) & 1u), f3 = (float)((c3 >> c) & 1u);
        f32x2 b0 = {f0, f0}, b1 = {f1, f1}, b2 = {f2, f2}, b3 = {f3, f3};
        const f32x2* wp = (const f32x2*)(Wb + pos * 24 + c * 8);
        #pragma unroll
        for (int ojp = 0; ojp < 4; ++ojp) {
          f32x2 w = wp[ojp];
          acc[0 + ojp]  = __builtin_elementwise_fma(b0, w, acc[0 + ojp]);
          acc[4 + ojp]  = __builtin_elementwise_fma(b1, w, acc[4 + ojp]);
          acc[8 + ojp]  = __builtin_elementwise_fma(b2, w, acc[8 + ojp]);
          acc[12 + ojp] = __builtin_elementwise_fma(b3, w, acc[12 + ojp]);
        }
      }
    }
  }

  float eps[8];
  #pragma unroll
  for (int oj = 0; oj < 8; ++oj) eps[oj] = EPS[og * 8 + oj];

  #pragma unroll
  for (int tt = 0; tt < 4; ++tt) {
    unsigned ab = 0, bb = 0;
    const int t = tq * 4 + tt;
    const int tbt = t * NB + b;
    #pragma unroll
    for (int oj = 0; oj < 8; ++oj) {
      f32x2 v = acc[tt * 4 + (oj >> 1)];
      float cur = ((oj & 1) ? v.y : v.x) * 0.25f;
      if (cur > 1.0f) ab |= 1u << oj;
      if (cur > 2.0f) bb |= 1u << oj;
      if (fabsf(cur - 1.0f) <= eps[oj] || fabsf(cur - 2.0f) <= eps[oj]) {
        uint32_t slot = atomicAdd(&cnt[0], 1u);
        if (slot < CAP_FIX) list1[slot] = make_uint2((uint32_t)(tbt * 196 + p),
                                                     (uint32_t)(og * 8 + oj));
      }
    }
    size_t idx = ((size_t)tbt * 196 + p) * 4 + og;
    A1[idx] = (unsigned char)ab;
    B1[idx] = (unsigned char)bb;
  }
}

// --- fixup 1: exact f64 recompute of flagged conv1 outputs, patch bits ----
__global__ __launch_bounds__(64) void fix1(const uint32_t* __restrict__ cnt,
                                           const uint2* __restrict__ list1,
                                           const unsigned char* __restrict__ spk0c,
                                           const double* __restrict__ W1R,
                                           uint32_t* __restrict__ A1w,
                                           uint32_t* __restrict__ B1w) {
  uint32_t total = cnt[0]; if (total > CAP_FIX) total = CAP_FIX;
  for (uint32_t i = blockIdx.x * 64 + threadIdx.x; i < total; i += gridDim.x * 64) {
    uint2 e = list1[i];
    uint32_t x = e.x, oc = e.y;
    int tb = x / 196, p = x % 196;
    int oh = p / 14, ow = p % 14;
    int og = oc >> 3, oj = oc & 7;
    const unsigned char* F = spk0c + (size_t)tb * 1024;
    double a = 0.0;
    for (int iy = 0; iy < 6; ++iy)
      for (int ix = 0; ix < 6; ++ix) {
        unsigned code = F[(2 * oh + iy) * 32 + 2 * ow + ix];
        for (int c = 0; c < 3; ++c) {
          double bd = (double)((code >> c) & 1u);
          a = fma(bd, W1R[og * 864 + (iy * 6 + ix) * 24 + c * 8 + oj], a);
        }
      }
    float cur = (float)(a * 0.25);
    uint32_t idx = x * 4 + og;
    uint32_t word = idx >> 2, shift = (idx & 3) * 8 + oj, m = 1u << shift;
    if (cur > 1.0f) atomicOr(&A1w[word], m); else atomicAnd(&A1w[word], ~m);
    if (cur > 2.0f) atomicOr(&B1w[word], m); else atomicAnd(&B1w[word], ~m);
  }
}

// --- LIF1 scan: batched register prefetch --------------------------------
__global__ __launch_bounds__(64) void scan1(const uint32_t* __restrict__ A1w,
                                            const uint32_t* __restrict__ B1w,
                                            uint32_t* __restrict__ mask1) {
  int chain = blockIdx.x * 64 + threadIdx.x;
  if (chain >= NB * 196) return;
  int b = chain / 196, p = chain % 196;
  const size_t stride = (size_t)NB * 196;
  size_t base = (size_t)b * 196 + p;
  uint32_t prev = 0;
  #pragma unroll
  for (int seg = 0; seg < 4; ++seg) {
    uint32_t Abuf[25], Bbuf[25];
    size_t sb = base + (size_t)(seg * 25) * stride;
    #pragma unroll
    for (int i = 0; i < 25; ++i) {
      Abuf[i] = A1w[sb + i * stride];
      Bbuf[i] = B1w[sb + i * stride];
    }
    #pragma unroll
    for (int i = 0; i < 25; ++i) {
      uint32_t s = (Abuf[i] & ~prev) | (Bbuf[i] & prev);
      mask1[sb + i * stride] = s;
      prev = s;
    }
  }
}

// --- conv2+pool f32: 10 t per block, 16 oc, skip from LDS tile ------------
__global__ __launch_bounds__(256, 4) void conv2_f32(const uint32_t* __restrict__ mask1,
                                                    const float* __restrict__ W2F,
                                                    const float* __restrict__ EPS,
                                                    unsigned char* __restrict__ A2,
                                                    unsigned char* __restrict__ B2,
                                                    uint32_t* __restrict__ cnt,
                                                    uint2* __restrict__ list2) {
  const int tc = blockIdx.x;   // 0..9
  const int b  = blockIdx.y;   // 0..63
  const int og = blockIdx.z;   // 0..3 -> oc og*16..+15
  const int t0 = tc * 10;
  __shared__ uint32_t sM[10 * 196];
  const int tid = threadIdx.x;

  for (int e = tid; e < 490; e += 256) {
    int fr = e / 49, w4 = e % 49;
    ((uint4*)sM)[e] =
        *((const uint4*)(mask1 + (size_t)((t0 + fr) * NB + b) * 196) + w4);
  }
  __syncthreads();

  const int lane = tid & 63;
  int thLo = (tid & ~63) / 25;
  int thHi = ((tid & ~63) + 63) / 25; if (thHi > 9) thHi = 9;
  uint32_t ca = 0;
  for (int e = thLo * 196 + lane; e < (thHi + 1) * 196; e += 64) ca |= sM[e];
  #pragma unroll
  for (int off = 32; off > 0; off >>= 1) ca |= __shfl_xor(ca, off);
  const uint32_t skipOr = ca;

  const int th = tid / 25, p = tid - th * 25;
  if (tid < 250) {
    const int oh = p / 5, ow = p - oh * 5;
    uint32_t m[36];
    const uint32_t* basep = &sM[th * 196 + (2 * oh) * 14 + 2 * ow];
    #pragma unroll
    for (int iy = 0; iy < 6; ++iy)
      #pragma unroll
      for (int ix = 0; ix < 6; ++ix) m[iy * 6 + ix] = basep[iy * 14 + ix];

    f32x2 acc[8];
    #pragma unroll
    for (int i = 0; i < 8; ++i) acc[i] = (f32x2)(0.0f);
    const float* Wb = W2F + (size_t)og * 18432;
    for (int c = 0; c < 32; ++c) {
      if (!((skipOr >> c) & 1u)) continue;
      const f32x2* wc = (const f32x2*)(Wb + c * 576);
      #pragma unroll
      for (int pos = 0; pos < 36; ++pos) {
        float bf = (float)((m[pos] >> c) & 1u);
        f32x2 bv = {bf, bf};
        const f32x2* wp = wc + pos * 8;
        #pragma unroll
        for (int ojp = 0; ojp < 8; ++ojp)
          acc[ojp] = __builtin_elementwise_fma(bv, wp[ojp], acc[ojp]);
      }
    }
    const int t = t0 + th;
    const int tbt = t * NB + b;
    unsigned ablo = 0, abhi = 0, bblo = 0, bbhi = 0;
    #pragma unroll
    for (int oj = 0; oj < 16; ++oj) {
      f32x2 v = acc[oj >> 1];
      float cur = ((oj & 1) ? v.y : v.x) * 0.25f;
      unsigned bit = 1u << (oj & 7);
      if (oj < 8) { if (cur > 1.0f) ablo |= bit; if (cur > 2.0f) bblo |= bit; }
      else       { if (cur > 1.0f) abhi |= bit; if (cur > 2.0f) bbhi |= bit; }
      float e = EPS[32 + og * 16 + oj];
      if (fabsf(cur - 1.0f) <= e || fabsf(cur - 2.0f) <= e) {
        uint32_t slot = atomicAdd(&cnt[1], 1u);
        if (slot < CAP_FIX) list2[slot] = make_uint2((uint32_t)(tbt * 25 + p),
                                                     (uint32_t)(og * 16 + oj));
      }
    }
    size_t idx = ((size_t)tbt * 25 + p) * 8 + og * 2;
    A2[idx] = (unsigned char)ablo; A2[idx + 1] = (unsigned char)abhi;
    B2[idx] = (unsigned char)bblo; B2[idx + 1] = (unsigned char)bbhi;
  }
}

// --- fixup 2: exact f64 recompute of flagged conv2 outputs ----------------
__global__ __launch_bounds__(64) void fix2(const uint32_t* __restrict__ cnt,
                                           const uint2* __restrict__ list2,
                                           const uint32_t* __restrict__ mask1,
                                           const double* __restrict__ W2R,
                                           uint32_t* __restrict__ A2w,
                                           uint32_t* __restrict__ B2w) {
  uint32_t total = cnt[1]; if (total > CAP_FIX) total = CAP_FIX;
  for (uint32_t i = blockIdx.x * 64 + threadIdx.x; i < total; i += gridDim.x * 64) {
    uint2 e = list2[i];
    uint32_t x = e.x, oc = e.y;
    int tb = x / 25, p = x % 25;
    int oh = p / 5, ow = p % 5;
    int og = oc >> 4, oj = oc & 15;
    const uint32_t* M = mask1 + (size_t)tb * 196;
    double a = 0.0;
    for (int c = 0; c < 32; ++c)
      for (int iy = 0; iy < 6; ++iy)
        for (int ix = 0; ix < 6; ++ix) {
          uint32_t mm = M[(2 * oh + iy) * 14 + 2 * ow + ix];
          double bd = (double)((mm >> c) & 1u);
          a = fma(bd, W2R[og * 18432 + c * 576 + (iy * 6 + ix) * 16 + oj], a);
        }
    float cur = (float)(a * 0.25);
    uint32_t idx = x * 8 + og * 2 + (oj >> 3);
    uint32_t word = idx >> 2, shift = (idx & 3) * 8 + (oj & 7), m = 1u << shift;
    if (cur > 1.0f) atomicOr(&A2w[word], m); else atomicAnd(&A2w[word], ~m);
    if (cur > 2.0f) atomicOr(&B2w[word], m); else atomicAnd(&B2w[word], ~m);
  }
}

// --- LIF2 scan ------------------------------------------------------------
__global__ __launch_bounds__(64) void scan2(const uint64_t* __restrict__ A2q,
                                            const uint64_t* __restrict__ B2q,
                                            uint64_t* __restrict__ mask2) {
  int chain = blockIdx.x * 64 + threadIdx.x;
  if (chain >= NB * 25) return;
  int b = chain / 25, p = chain % 25;
  const size_t stride = (size_t)NB * 25;
  size_t base = (size_t)b * 25 + p;
  uint64_t prev = 0;
  #pragma unroll
  for (int seg = 0; seg < 4; ++seg) {
    uint64_t Abuf[25], Bbuf[25];
    size_t sb = base + (size_t)(seg * 25) * stride;
    #pragma unroll
    for (int i = 0; i < 25; ++i) {
      Abuf[i] = A2q[sb + i * stride];
      Bbuf[i] = B2q[sb + i * stride];
    }
    #pragma unroll
    for (int i = 0; i < 25; ++i) {
      uint64_t s = (Abuf[i] & ~prev) | (Bbuf[i] & prev);
      mask2[sb + i * stride] = s;
      prev = s;
    }
  }
}

// --- FC from packed masks: cur3[t,b,10] (exact f64) -----------------------
__global__ __launch_bounds__(256) void fc_kernel(const uint64_t* __restrict__ mask2,
                                                 const float* __restrict__ W2,
                                                 float* __restrict__ cur3) {
  int gid = blockIdx.x * 256 + threadIdx.x;
  if (gid >= NSTEPS * NB * 10) return;
  int tb = gid / 10, o = gid % 10;
  const uint64_t* m = mask2 + (size_t)tb * 25;
  const float* w = W2 + o * 1600;
  double acc = 0.0;
  for (int p = 0; p < 25; ++p) {
    uint64_t mw = m[p];
    uint32_t lo = (uint32_t)mw, hi = (uint32_t)(mw >> 32);
    #pragma unroll 8
    for (int oc = 0; oc < 32; ++oc) {
      double bd = (double)((lo >> oc) & 1u);
      acc = fma(bd, (double)w[oc * 25 + p], acc);
    }
    #pragma unroll 8
    for (int oc = 32; oc < 64; ++oc) {
      double bd = (double)((hi >> (oc - 32)) & 1u);
      acc = fma(bd, (double)w[oc * 25 + p], acc);
    }
  }
  cur3[gid] = (float)acc;
}

// --- LIF3: out spikes [100,64,10] then mem [100,64,10] --------------------
__global__ __launch_bounds__(256) void lif3_kernel(const float* __restrict__ cur3,
                                                   float* __restrict__ out) {
  int bo = blockIdx.x * 256 + threadIdx.x;
  if (bo >= NB * 10) return;
  float prev = 0.0f;
  for (int t = 0; t < NSTEPS; ++t) {
    float cur = cur3[t * (NB * 10) + bo];
    float mem = cur - prev;
    bool s = mem > 1.0f;
    out[t * (NB * 10) + bo] = s ? 1.0f : 0.0f;
    out[NSTEPS * NB * 10 + t * (NB * 10) + bo] = mem;
    prev = s ? 1.0f : 0.0f;
  }
}

extern "C" void kernel_launch(void* const* d_in, const int* in_sizes, int n_in,
                              void* d_out, int out_size, void* d_ws, size_t ws_size,
                              hipStream_t stream) {
  const float* x    = (const float*)d_in[0];
  const float* W_in = (const float*)d_in[1];
  const float* W_h1 = (const float*)d_in[2];
  const float* W_h2 = (const float*)d_in[3];
  float* out = (float*)d_out;

  unsigned char* ws = (unsigned char*)d_ws;
  double*        W1R   = (double*)(ws + 0);           //     27,648
  double*        W2R   = (double*)(ws + 27648);       //    589,824
  float*         W1F   = (float*)(ws + 617472);       //     13,824
  float*         W2F   = (float*)(ws + 631296);       //    294,912
  float*         EPS   = (float*)(ws + 926208);       //        384
  uint32_t*      cnt   = (uint32_t*)(ws + 926592);    //          8 (pad 128)
  unsigned char* spk0c = ws + 926720;                 //  6,553,600
  unsigned char* A1    = ws + 7480320;                //  5,017,600
  unsigned char* B1    = ws + 12497920;               //  5,017,600
  uint32_t*      mask1 = (uint32_t*)(ws + 17515520);  //  5,017,600
  unsigned char* A2    = ws + 22533120;               //  1,280,000
  unsigned char* B2    = ws + 23813120;               //  1,280,000
  uint64_t*      mask2 = (uint64_t*)(ws + 25093120);  //  1,280,000
  float*         cur3  = (float*)(ws + 26373120);     //    256,000
  uint2*         list1 = (uint2*)(ws + 26629120);     //  8,388,608
  uint2*         list2 = (uint2*)(ws + 35017728);     //  8,388,608  (end ~43.4 MB)

  weff_all<<<302, 256, 0, stream>>>(W_in, W_h1, W1R, W2R, W1F, W2F);
  eps_kernel<<<1, 128, 0, stream>>>(W1R, W2R, EPS);
  gen_spikes<<<NSTEPS * NB * 4, 256, 0, stream>>>(x, spk0c);
  hipMemsetAsync(cnt, 0, 8, stream);
  conv1_f32<<<dim3(1225, 4), 256, 0, stream>>>(spk0c, W1F, EPS, A1, B1, cnt, list1);
  fix1<<<2048, 64, 0, stream>>>(cnt, list1, spk0c, W1R, (uint32_t*)A1, (uint32_t*)B1);
  scan1<<<(NB * 196 + 63) / 64, 64, 0, stream>>>((const uint32_t*)A1,
                                                 (const uint32_t*)B1, mask1);
  conv2_f32<<<dim3(10, NB, 4), 256, 0, stream>>>(mask1, W2F, EPS, A2, B2, cnt, list2);
  fix2<<<2048, 64, 0, stream>>>(cnt, list2, mask1, W2R, (uint32_t*)A2, (uint32_t*)B2);
  scan2<<<(NB * 25 + 63) / 64, 64, 0, stream>>>((const uint64_t*)A2,
                                                (const uint64_t*)B2, mask2);
  fc_kernel<<<(NSTEPS * NB * 10 + 255) / 256, 256, 0, stream>>>(mask2, W_h2, cur3);
  lif3_kernel<<<3, 256, 0, stream>>>(cur3, out);
}

// Round 8
// 610.706 us; speedup vs baseline: 5.1462x; 5.1462x over previous
//
#include <hip/hip_runtime.h>
#include <stdint.h>

// ---------------------------------------------------------------------------
// Conv-SNN, 100 steps, B=64, BETA=0.
// Round 8: f32 convs (pk-fma) with scratch-proof epilogues:
//  - acc -> scalar cur[] extraction in a clean unrolled loop (no dynamic
//    indexing / atomics near the accumulator array -> no scratch demotion,
//    which caused round 7's 10 GB/dispatch spill traffic)
//  - near-threshold outputs marked in DENSE flag-byte arrays F1/F2 (no
//    atomics, no lists); fix kernels scan F and patch bits with exact f64.
//  - conv1 weights staged in LDS.
// Bits provably exact (6x-margin interval + f64 fixup); downstream kernels
// unchanged from round 6 (absmax 0.0 lineage).
// ---------------------------------------------------------------------------

#define NSTEPS 100
#define NB 64

typedef float f32x2 __attribute__((ext_vector_type(2)));

__device__ __forceinline__ uint32_t rotl32(uint32_t v, uint32_t r) {
  return (v << r) | (v >> (32u - r));
}

__device__ __forceinline__ void threefry2x32(uint32_t k0, uint32_t k1,
                                             uint32_t& x0, uint32_t& x1) {
  uint32_t k2 = k0 ^ k1 ^ 0x1BD11BDAu;
  x0 += k0; x1 += k1;
#define TF_R(r) { x0 += x1; x1 = rotl32(x1, r); x1 ^= x0; }
  TF_R(13u) TF_R(15u) TF_R(26u) TF_R(6u)
  x0 += k1; x1 += k2 + 1u;
  TF_R(17u) TF_R(29u) TF_R(16u) TF_R(24u)
  x0 += k2; x1 += k0 + 2u;
  TF_R(13u) TF_R(15u) TF_R(26u) TF_R(6u)
  x0 += k0; x1 += k1 + 3u;
  TF_R(17u) TF_R(29u) TF_R(16u) TF_R(24u)
  x0 += k1; x1 += k2 + 4u;
  TF_R(13u) TF_R(15u) TF_R(26u) TF_R(6u)
  x0 += k2; x1 += k0 + 5u;
#undef TF_R
}

__device__ __forceinline__ double fold_pool_w(const float* W, int base, int pos) {
  int iy = pos / 6, ix = pos % 6;
  double w = 0.0;
  for (int dy = 0; dy < 2; ++dy) {
    int ky = iy - dy; if (ky < 0 || ky > 4) continue;
    for (int dx = 0; dx < 2; ++dx) {
      int kx = ix - dx; if (kx < 0 || kx > 4) continue;
      w += (double)W[base + ky * 5 + kx];
    }
  }
  return w;
}

// Folded-pool weights, f64 masters + f32 copies.
// W1R/W1F: [og4][pos36][c3][oj8]   (oc = og*8+oj)
// W2R/W2F: [og4][c32][pos36][oj16] (oc = og*16+oj)
__global__ __launch_bounds__(256) void weff_all(const float* __restrict__ W_in,
                                                const float* __restrict__ W_h1,
                                                double* __restrict__ W1R,
                                                double* __restrict__ W2R,
                                                float* __restrict__ W1F,
                                                float* __restrict__ W2F) {
  int e = blockIdx.x * 256 + threadIdx.x;
  if (e < 3456) {
    int oj = e & 7, c = (e >> 3) % 3, pos = ((e >> 3) / 3) % 36, og = (e >> 3) / 108;
    int oc = og * 8 + oj;
    double w = fold_pool_w(W_in, (oc * 3 + c) * 25, pos);
    W1R[e] = w; W1F[e] = (float)w;
  } else if (e < 3456 + 73728) {
    int e2 = e - 3456;
    int oj = e2 & 15, pos = (e2 >> 4) % 36, c = ((e2 >> 4) / 36) % 32, og = e2 / 18432;
    int oc = og * 16 + oj;
    double w = fold_pool_w(W_h1, (oc * 32 + c) * 25, pos);
    W2R[e2] = w; W2F[e2] = (float)w;
  }
}

// EPS[0..31]: conv1 per-oc flag radius; EPS[32..95]: conv2 per-oc.
__global__ __launch_bounds__(128) void eps_kernel(const double* __restrict__ W1R,
                                                  const double* __restrict__ W2R,
                                                  float* __restrict__ EPS) {
  int oc = blockIdx.x * 128 + threadIdx.x;
  const double u24 = 5.9604644775390625e-08;
  if (oc < 32) {
    int og = oc >> 3, oj = oc & 7;
    double S = 0.0;
    for (int pos = 0; pos < 36; ++pos)
      for (int c = 0; c < 3; ++c) S += fabs(W1R[og * 864 + pos * 24 + c * 8 + oj]);
    EPS[oc] = (float)(S * (108.0 * u24 * 6.0) * 0.25);
  } else if (oc < 96) {
    int o = oc - 32, og = o >> 4, oj = o & 15;
    double S = 0.0;
    for (int c = 0; c < 32; ++c)
      for (int pos = 0; pos < 36; ++pos) S += fabs(W2R[og * 18432 + c * 576 + pos * 16 + oj]);
    EPS[oc] = (float)(S * (1152.0 * u24 * 6.0) * 0.25);
  }
}

// --- spike gen: per-pixel 3-bit channel codes [t,b,1024] bytes ------------
__global__ __launch_bounds__(256) void gen_spikes(const float* __restrict__ x,
                                                  unsigned char* __restrict__ spk0c) {
  int g = blockIdx.x * 256 + threadIdx.x;
  if (g >= NSTEPS * NB * 1024) return;
  int tb = g >> 10, pix = g & 1023;
  int b = tb & 63;
  unsigned code = 0;
  #pragma unroll
  for (int c = 0; c < 3; ++c) {
    uint32_t i = (uint32_t)((tb * 3 + c) * 1024 + pix);
    uint32_t x0 = 0u, x1 = i;
    threefry2x32(0u, 1u, x0, x1);
    uint32_t bits = x0 ^ x1;
    float u = __uint_as_float((bits >> 9) | 0x3f800000u) - 1.0f;
    float xv = x[(b * 3 + c) * 1024 + pix];
    code |= (u < 2.0f * xv) ? (1u << c) : 0u;
  }
  spk0c[g] = (unsigned char)code;
}

// --- conv1+pool f32, 4 t per thread, LDS weights, dense flags -------------
__global__ __launch_bounds__(256, 4) void conv1_f32(const unsigned char* __restrict__ spk0c,
                                                    const float* __restrict__ W1F,
                                                    const float* __restrict__ EPS,
                                                    unsigned char* __restrict__ A1,
                                                    unsigned char* __restrict__ B1,
                                                    unsigned char* __restrict__ F1) {
  const int og  = blockIdx.y;
  const int tid = threadIdx.x;
  const int id0 = blockIdx.x * 256;
  const int id  = id0 + tid;
  const int tb0 = id0 / 196;
  __shared__ unsigned char sC[3][4][1024];
  __shared__ float sW[864];

  if (tid < 216) ((float4*)sW)[tid] = ((const float4*)(W1F + og * 864))[tid];
  #pragma unroll
  for (int k = 0; k < 3; ++k) {
    int idx = tid + k * 256;
    int fi = idx >> 6, lane = idx & 63;
    int seg = fi >> 2, tt = fi & 3;
    int tb = tb0 + seg; if (tb > 1599) tb = 1599;
    int b = tb & 63, tq = tb >> 6;
    ((uint4*)sC)[idx] =
        ((const uint4*)(spk0c + (size_t)((tq * 4 + tt) * NB + b) * 1024))[lane];
  }
  __syncthreads();

  const int tb  = id / 196;
  const int p   = id - tb * 196;
  const int seg = tb - tb0;
  const int b = tb & 63, tq = tb >> 6;
  const int oh = p / 14, ow = p - oh * 14;
  const unsigned char* base = &sC[seg][0][(2 * oh) * 32 + 2 * ow];

  f32x2 acc[16];
  #pragma unroll
  for (int i = 0; i < 16; ++i) acc[i] = (f32x2)(0.0f);

  #pragma unroll
  for (int iy = 0; iy < 6; ++iy) {
    #pragma unroll
    for (int ix = 0; ix < 6; ++ix) {
      const int pos = iy * 6 + ix, off = iy * 32 + ix;
      unsigned c0 = base[0 * 1024 + off];
      unsigned c1 = base[1 * 1024 + off];
      unsigned c2 = base[2 * 1024 + off];
      unsigned c3 = base[3 * 1024 + off];
      #pragma unroll
      for (int c = 0; c < 3; ++c) {
        float f0 = (float)((c0 >> c) & 1u), f1 = (float)((c1 >> c) & 1u);
        float f2 = (float)((c2 >> c) & 1u), f3 = (float)((c3 >> c) & 1u);
        f32x2 b0 = {f0, f0}, b1 = {f1, f1}, b2 = {f2, f2}, b3 = {f3, f3};
        const f32x2* wp = (const f32x2*)(&sW[pos * 24 + c * 8]);
        #pragma unroll
        for (int ojp = 0; ojp < 4; ++ojp) {
          f32x2 w = wp[ojp];
          acc[0 + ojp]  = __builtin_elementwise_fma(b0, w, acc[0 + ojp]);
          acc[4 + ojp]  = __builtin_elementwise_fma(b1, w, acc[4 + ojp]);
          acc[8 + ojp]  = __builtin_elementwise_fma(b2, w, acc[8 + ojp]);
          acc[12 + ojp] = __builtin_elementwise_fma(b3, w, acc[12 + ojp]);
        }
      }
    }
  }

  // clean scalar extraction — acc never touched after this
  float cur[32];
  #pragma unroll
  for (int tt = 0; tt < 4; ++tt)
    #pragma unroll
    for (int ojp = 0; ojp < 4; ++ojp) {
      f32x2 v = acc[tt * 4 + ojp];
      cur[tt * 8 + 2 * ojp]     = v.x * 0.25f;
      cur[tt * 8 + 2 * ojp + 1] = v.y * 0.25f;
    }

  float eps[8];
  #pragma unroll
  for (int oj = 0; oj < 8; ++oj) eps[oj] = EPS[og * 8 + oj];

  #pragma unroll
  for (int tt = 0; tt < 4; ++tt) {
    unsigned ab = 0, bb = 0, fb = 0;
    #pragma unroll
    for (int oj = 0; oj < 8; ++oj) {
      float c = cur[tt * 8 + oj];
      if (c > 1.0f) ab |= 1u << oj;
      if (c > 2.0f) bb |= 1u << oj;
      if (fabsf(c - 1.0f) <= eps[oj] || fabsf(c - 2.0f) <= eps[oj]) fb |= 1u << oj;
    }
    const int t = tq * 4 + tt;
    size_t idx = ((size_t)(t * NB + b) * 196 + p) * 4 + og;
    A1[idx] = (unsigned char)ab;
    B1[idx] = (unsigned char)bb;
    F1[idx] = (unsigned char)fb;
  }
}

// --- fixup 1: scan F1, exact f64 recompute, patch A1/B1 bits --------------
__global__ __launch_bounds__(256) void fix1(const uint32_t* __restrict__ F1w,
                                            const unsigned char* __restrict__ spk0c,
                                            const double* __restrict__ W1R,
                                            unsigned char* __restrict__ A1,
                                            unsigned char* __restrict__ B1) {
  int wi = blockIdx.x * 256 + threadIdx.x;
  if (wi >= 1254400) return;  // 5,017,600 / 4
  uint32_t w = F1w[wi];
  if (!w) return;
  for (int k = 0; k < 4; ++k) {
    unsigned fb = (w >> (k * 8)) & 0xffu;
    if (!fb) continue;
    int byteIdx = wi * 4 + k;
    int og = byteIdx & 3, x = byteIdx >> 2;
    int tb = x / 196, p = x % 196;
    int oh = p / 14, ow = p % 14;
    const unsigned char* F = spk0c + (size_t)tb * 1024;
    unsigned a = A1[byteIdx], bbyte = B1[byteIdx];
    for (int oj = 0; oj < 8; ++oj) {
      if (!((fb >> oj) & 1u)) continue;
      double acc = 0.0;
      for (int iy = 0; iy < 6; ++iy)
        for (int ix = 0; ix < 6; ++ix) {
          unsigned code = F[(2 * oh + iy) * 32 + 2 * ow + ix];
          for (int c = 0; c < 3; ++c) {
            double bd = (double)((code >> c) & 1u);
            acc = fma(bd, W1R[og * 864 + (iy * 6 + ix) * 24 + c * 8 + oj], acc);
          }
        }
      float cur = (float)(acc * 0.25);
      unsigned m = 1u << oj;
      a = (cur > 1.0f) ? (a | m) : (a & ~m);
      bbyte = (cur > 2.0f) ? (bbyte | m) : (bbyte & ~m);
    }
    A1[byteIdx] = (unsigned char)a;
    B1[byteIdx] = (unsigned char)bbyte;
  }
}

// --- LIF1 scan: batched register prefetch --------------------------------
__global__ __launch_bounds__(64) void scan1(const uint32_t* __restrict__ A1w,
                                            const uint32_t* __restrict__ B1w,
                                            uint32_t* __restrict__ mask1) {
  int chain = blockIdx.x * 64 + threadIdx.x;
  if (chain >= NB * 196) return;
  int b = chain / 196, p = chain % 196;
  const size_t stride = (size_t)NB * 196;
  size_t base = (size_t)b * 196 + p;
  uint32_t prev = 0;
  #pragma unroll
  for (int seg = 0; seg < 4; ++seg) {
    uint32_t Abuf[25], Bbuf[25];
    size_t sb = base + (size_t)(seg * 25) * stride;
    #pragma unroll
    for (int i = 0; i < 25; ++i) {
      Abuf[i] = A1w[sb + i * stride];
      Bbuf[i] = B1w[sb + i * stride];
    }
    #pragma unroll
    for (int i = 0; i < 25; ++i) {
      uint32_t s = (Abuf[i] & ~prev) | (Bbuf[i] & prev);
      mask1[sb + i * stride] = s;
      prev = s;
    }
  }
}

// --- conv2+pool f32: 10 t per block, 16 oc, skip, dense flags -------------
__global__ __launch_bounds__(256, 4) void conv2_f32(const uint32_t* __restrict__ mask1,
                                                    const float* __restrict__ W2F,
                                                    const float* __restrict__ EPS,
                                                    unsigned char* __restrict__ A2,
                                                    unsigned char* __restrict__ B2,
                                                    unsigned char* __restrict__ F2) {
  const int tc = blockIdx.x;   // 0..9
  const int b  = blockIdx.y;   // 0..63
  const int og = blockIdx.z;   // 0..3 -> oc og*16..+15
  const int t0 = tc * 10;
  __shared__ uint32_t sM[10 * 196];
  const int tid = threadIdx.x;

  for (int e = tid; e < 490; e += 256) {
    int fr = e / 49, w4 = e % 49;
    ((uint4*)sM)[e] =
        *((const uint4*)(mask1 + (size_t)((t0 + fr) * NB + b) * 196) + w4);
  }
  __syncthreads();

  const int lane = tid & 63;
  int thLo = (tid & ~63) / 25;
  int thHi = ((tid & ~63) + 63) / 25; if (thHi > 9) thHi = 9;
  uint32_t ca = 0;
  for (int e = thLo * 196 + lane; e < (thHi + 1) * 196; e += 64) ca |= sM[e];
  #pragma unroll
  for (int off = 32; off > 0; off >>= 1) ca |= __shfl_xor(ca, off);
  const uint32_t skipOr = ca;

  const int th = tid / 25, p = tid - th * 25;
  if (tid < 250) {
    const int oh = p / 5, ow = p - oh * 5;
    uint32_t m[36];
    const uint32_t* basep = &sM[th * 196 + (2 * oh) * 14 + 2 * ow];
    #pragma unroll
    for (int iy = 0; iy < 6; ++iy)
      #pragma unroll
      for (int ix = 0; ix < 6; ++ix) m[iy * 6 + ix] = basep[iy * 14 + ix];

    f32x2 acc[8];
    #pragma unroll
    for (int i = 0; i < 8; ++i) acc[i] = (f32x2)(0.0f);
    const float* Wb = W2F + (size_t)og * 18432;
    for (int c = 0; c < 32; ++c) {
      if (!((skipOr >> c) & 1u)) continue;
      const f32x2* wc = (const f32x2*)(Wb + c * 576);
      #pragma unroll
      for (int pos = 0; pos < 36; ++pos) {
        float bf = (float)((m[pos] >> c) & 1u);
        f32x2 bv = {bf, bf};
        const f32x2* wp = wc + pos * 8;
        #pragma unroll
        for (int ojp = 0; ojp < 8; ++ojp)
          acc[ojp] = __builtin_elementwise_fma(bv, wp[ojp], acc[ojp]);
      }
    }

    // clean scalar extraction — acc never touched after this
    float cur[16];
    #pragma unroll
    for (int i = 0; i < 8; ++i) {
      f32x2 v = acc[i];
      cur[2 * i]     = v.x * 0.25f;
      cur[2 * i + 1] = v.y * 0.25f;
    }

    unsigned ab0 = 0, ab1 = 0, bb0 = 0, bb1 = 0, fb0 = 0, fb1 = 0;
    #pragma unroll
    for (int oj = 0; oj < 8; ++oj) {
      float cl = cur[oj], e0 = EPS[32 + og * 16 + oj];
      if (cl > 1.0f) ab0 |= 1u << oj;
      if (cl > 2.0f) bb0 |= 1u << oj;
      if (fabsf(cl - 1.0f) <= e0 || fabsf(cl - 2.0f) <= e0) fb0 |= 1u << oj;
      float ch = cur[8 + oj], e1 = EPS[32 + og * 16 + 8 + oj];
      if (ch > 1.0f) ab1 |= 1u << oj;
      if (ch > 2.0f) bb1 |= 1u << oj;
      if (fabsf(ch - 1.0f) <= e1 || fabsf(ch - 2.0f) <= e1) fb1 |= 1u << oj;
    }
    const int t = t0 + th;
    size_t idx = ((size_t)(t * NB + b) * 25 + p) * 8 + og * 2;
    A2[idx] = (unsigned char)ab0; A2[idx + 1] = (unsigned char)ab1;
    B2[idx] = (unsigned char)bb0; B2[idx + 1] = (unsigned char)bb1;
    F2[idx] = (unsigned char)fb0; F2[idx + 1] = (unsigned char)fb1;
  }
}

// --- fixup 2: scan F2, exact f64 recompute, patch A2/B2 bits --------------
__global__ __launch_bounds__(256) void fix2(const uint32_t* __restrict__ F2w,
                                            const uint32_t* __restrict__ mask1,
                                            const double* __restrict__ W2R,
                                            unsigned char* __restrict__ A2,
                                            unsigned char* __restrict__ B2) {
  int wi = blockIdx.x * 256 + threadIdx.x;
  if (wi >= 320000) return;  // 1,280,000 / 4
  uint32_t w = F2w[wi];
  if (!w) return;
  for (int k = 0; k < 4; ++k) {
    unsigned fb = (w >> (k * 8)) & 0xffu;
    if (!fb) continue;
    int byteIdx = wi * 4 + k;
    int og2 = byteIdx & 7, og = og2 >> 1, h = og2 & 1;
    int x = byteIdx >> 3;
    int tb = x / 25, p = x % 25;
    int oh = p / 5, ow = p % 5;
    const uint32_t* M = mask1 + (size_t)tb * 196;
    unsigned a = A2[byteIdx], bbyte = B2[byteIdx];
    for (int bit = 0; bit < 8; ++bit) {
      if (!((fb >> bit) & 1u)) continue;
      int oj = h * 8 + bit;
      double acc = 0.0;
      for (int c = 0; c < 32; ++c)
        for (int iy = 0; iy < 6; ++iy)
          for (int ix = 0; ix < 6; ++ix) {
            uint32_t mm = M[(2 * oh + iy) * 14 + 2 * ow + ix];
            double bd = (double)((mm >> c) & 1u);
            acc = fma(bd, W2R[og * 18432 + c * 576 + (iy * 6 + ix) * 16 + oj], acc);
          }
      float cur = (float)(acc * 0.25);
      unsigned m = 1u << bit;
      a = (cur > 1.0f) ? (a | m) : (a & ~m);
      bbyte = (cur > 2.0f) ? (bbyte | m) : (bbyte & ~m);
    }
    A2[byteIdx] = (unsigned char)a;
    B2[byteIdx] = (unsigned char)bbyte;
  }
}

// --- LIF2 scan ------------------------------------------------------------
__global__ __launch_bounds__(64) void scan2(const uint64_t* __restrict__ A2q,
                                            const uint64_t* __restrict__ B2q,
                                            uint64_t* __restrict__ mask2) {
  int chain = blockIdx.x * 64 + threadIdx.x;
  if (chain >= NB * 25) return;
  int b = chain / 25, p = chain % 25;
  const size_t stride = (size_t)NB * 25;
  size_t base = (size_t)b * 25 + p;
  uint64_t prev = 0;
  #pragma unroll
  for (int seg = 0; seg < 4; ++seg) {
    uint64_t Abuf[25], Bbuf[25];
    size_t sb = base + (size_t)(seg * 25) * stride;
    #pragma unroll
    for (int i = 0; i < 25; ++i) {
      Abuf[i] = A2q[sb + i * stride];
      Bbuf[i] = B2q[sb + i * stride];
    }
    #pragma unroll
    for (int i = 0; i < 25; ++i) {
      uint64_t s = (Abuf[i] & ~prev) | (Bbuf[i] & prev);
      mask2[sb + i * stride] = s;
      prev = s;
    }
  }
}

// --- FC from packed masks: cur3[t,b,10] (exact f64) -----------------------
__global__ __launch_bounds__(256) void fc_kernel(const uint64_t* __restrict__ mask2,
                                                 const float* __restrict__ W2,
                                                 float* __restrict__ cur3) {
  int gid = blockIdx.x * 256 + threadIdx.x;
  if (gid >= NSTEPS * NB * 10) return;
  int tb = gid / 10, o = gid % 10;
  const uint64_t* m = mask2 + (size_t)tb * 25;
  const float* w = W2 + o * 1600;
  double acc = 0.0;
  for (int p = 0; p < 25; ++p) {
    uint64_t mw = m[p];
    uint32_t lo = (uint32_t)mw, hi = (uint32_t)(mw >> 32);
    #pragma unroll 8
    for (int oc = 0; oc < 32; ++oc) {
      double bd = (double)((lo >> oc) & 1u);
      acc = fma(bd, (double)w[oc * 25 + p], acc);
    }
    #pragma unroll 8
    for (int oc = 32; oc < 64; ++oc) {
      double bd = (double)((hi >> (oc - 32)) & 1u);
      acc = fma(bd, (double)w[oc * 25 + p], acc);
    }
  }
  cur3[gid] = (float)acc;
}

// --- LIF3: out spikes [100,64,10] then mem [100,64,10] --------------------
__global__ __launch_bounds__(256) void lif3_kernel(const float* __restrict__ cur3,
                                                   float* __restrict__ out) {
  int bo = blockIdx.x * 256 + threadIdx.x;
  if (bo >= NB * 10) return;
  float prev = 0.0f;
  for (int t = 0; t < NSTEPS; ++t) {
    float cur = cur3[t * (NB * 10) + bo];
    float mem = cur - prev;
    bool s = mem > 1.0f;
    out[t * (NB * 10) + bo] = s ? 1.0f : 0.0f;
    out[NSTEPS * NB * 10 + t * (NB * 10) + bo] = mem;
    prev = s ? 1.0f : 0.0f;
  }
}

extern "C" void kernel_launch(void* const* d_in, const int* in_sizes, int n_in,
                              void* d_out, int out_size, void* d_ws, size_t ws_size,
                              hipStream_t stream) {
  const float* x    = (const float*)d_in[0];
  const float* W_in = (const float*)d_in[1];
  const float* W_h1 = (const float*)d_in[2];
  const float* W_h2 = (const float*)d_in[3];
  float* out = (float*)d_out;

  unsigned char* ws = (unsigned char*)d_ws;
  double*        W1R   = (double*)(ws + 0);           //     27,648
  double*        W2R   = (double*)(ws + 27648);       //    589,824
  float*         W1F   = (float*)(ws + 617472);       //     13,824
  float*         W2F   = (float*)(ws + 631296);       //    294,912
  float*         EPS   = (float*)(ws + 926208);       //        384 (pad 128)
  unsigned char* spk0c = ws + 926720;                 //  6,553,600
  unsigned char* A1    = ws + 7480320;                //  5,017,600
  unsigned char* B1    = ws + 12497920;               //  5,017,600
  unsigned char* F1    = ws + 17515520;               //  5,017,600
  uint32_t*      mask1 = (uint32_t*)(ws + 22533120);  //  5,017,600
  unsigned char* A2    = ws + 27550720;               //  1,280,000
  unsigned char* B2    = ws + 28830720;               //  1,280,000
  unsigned char* F2    = ws + 30110720;               //  1,280,000
  uint64_t*      mask2 = (uint64_t*)(ws + 31390720);  //  1,280,000
  float*         cur3  = (float*)(ws + 32670720);     //    256,000 (end ~33 MB)

  weff_all<<<302, 256, 0, stream>>>(W_in, W_h1, W1R, W2R, W1F, W2F);
  eps_kernel<<<1, 128, 0, stream>>>(W1R, W2R, EPS);
  gen_spikes<<<NSTEPS * NB * 4, 256, 0, stream>>>(x, spk0c);
  conv1_f32<<<dim3(1225, 4), 256, 0, stream>>>(spk0c, W1F, EPS, A1, B1, F1);
  fix1<<<(1254400 + 255) / 256, 256, 0, stream>>>((const uint32_t*)F1, spk0c, W1R, A1, B1);
  scan1<<<(NB * 196 + 63) / 64, 64, 0, stream>>>((const uint32_t*)A1,
                                                 (const uint32_t*)B1, mask1);
  conv2_f32<<<dim3(10, NB, 4), 256, 0, stream>>>(mask1, W2F, EPS, A2, B2, F2);
  fix2<<<(320000 + 255) / 256, 256, 0, stream>>>((const uint32_t*)F2, mask1, W2R, A2, B2);
  scan2<<<(NB * 25 + 63) / 64, 64, 0, stream>>>((const uint64_t*)A2,
                                                (const uint64_t*)B2, mask2);
  fc_kernel<<<(NSTEPS * NB * 10 + 255) / 256, 256, 0, stream>>>(mask2, W_h2, cur3);
  lif3_kernel<<<3, 256, 0, stream>>>(cur3, out);
}

// Round 9
// 477.600 us; speedup vs baseline: 6.5805x; 1.2787x over previous
//
#include <hip/hip_runtime.h>
#include <stdint.h>

// ---------------------------------------------------------------------------
// Conv-SNN, 100 steps, B=64, BETA=0.
// Round 9: round 8 + latency fixes for the serial-chain kernels:
//  - fc: 8-way k-split (thread owns 8 oc), 25-word mask prefetch, 8
//    independent FMA chains, wave shfl_xor reduce -> 512k threads.
//  - lif3: batch-prefetch scan (64-thread blocks, 25-deep segments).
// Convs/fixups/scans unchanged from round 8 (absmax 0.0 lineage).
// ---------------------------------------------------------------------------

#define NSTEPS 100
#define NB 64

typedef float f32x2 __attribute__((ext_vector_type(2)));

__device__ __forceinline__ uint32_t rotl32(uint32_t v, uint32_t r) {
  return (v << r) | (v >> (32u - r));
}

__device__ __forceinline__ void threefry2x32(uint32_t k0, uint32_t k1,
                                             uint32_t& x0, uint32_t& x1) {
  uint32_t k2 = k0 ^ k1 ^ 0x1BD11BDAu;
  x0 += k0; x1 += k1;
#define TF_R(r) { x0 += x1; x1 = rotl32(x1, r); x1 ^= x0; }
  TF_R(13u) TF_R(15u) TF_R(26u) TF_R(6u)
  x0 += k1; x1 += k2 + 1u;
  TF_R(17u) TF_R(29u) TF_R(16u) TF_R(24u)
  x0 += k2; x1 += k0 + 2u;
  TF_R(13u) TF_R(15u) TF_R(26u) TF_R(6u)
  x0 += k0; x1 += k1 + 3u;
  TF_R(17u) TF_R(29u) TF_R(16u) TF_R(24u)
  x0 += k1; x1 += k2 + 4u;
  TF_R(13u) TF_R(15u) TF_R(26u) TF_R(6u)
  x0 += k2; x1 += k0 + 5u;
#undef TF_R
}

__device__ __forceinline__ double fold_pool_w(const float* W, int base, int pos) {
  int iy = pos / 6, ix = pos % 6;
  double w = 0.0;
  for (int dy = 0; dy < 2; ++dy) {
    int ky = iy - dy; if (ky < 0 || ky > 4) continue;
    for (int dx = 0; dx < 2; ++dx) {
      int kx = ix - dx; if (kx < 0 || kx > 4) continue;
      w += (double)W[base + ky * 5 + kx];
    }
  }
  return w;
}

// Folded-pool weights, f64 masters + f32 copies.
// W1R/W1F: [og4][pos36][c3][oj8]   (oc = og*8+oj)
// W2R/W2F: [og4][c32][pos36][oj16] (oc = og*16+oj)
__global__ __launch_bounds__(256) void weff_all(const float* __restrict__ W_in,
                                                const float* __restrict__ W_h1,
                                                double* __restrict__ W1R,
                                                double* __restrict__ W2R,
                                                float* __restrict__ W1F,
                                                float* __restrict__ W2F) {
  int e = blockIdx.x * 256 + threadIdx.x;
  if (e < 3456) {
    int oj = e & 7, c = (e >> 3) % 3, pos = ((e >> 3) / 3) % 36, og = (e >> 3) / 108;
    int oc = og * 8 + oj;
    double w = fold_pool_w(W_in, (oc * 3 + c) * 25, pos);
    W1R[e] = w; W1F[e] = (float)w;
  } else if (e < 3456 + 73728) {
    int e2 = e - 3456;
    int oj = e2 & 15, pos = (e2 >> 4) % 36, c = ((e2 >> 4) / 36) % 32, og = e2 / 18432;
    int oc = og * 16 + oj;
    double w = fold_pool_w(W_h1, (oc * 32 + c) * 25, pos);
    W2R[e2] = w; W2F[e2] = (float)w;
  }
}

// EPS[0..31]: conv1 per-oc flag radius; EPS[32..95]: conv2 per-oc.
__global__ __launch_bounds__(128) void eps_kernel(const double* __restrict__ W1R,
                                                  const double* __restrict__ W2R,
                                                  float* __restrict__ EPS) {
  int oc = blockIdx.x * 128 + threadIdx.x;
  const double u24 = 5.9604644775390625e-08;
  if (oc < 32) {
    int og = oc >> 3, oj = oc & 7;
    double S = 0.0;
    for (int pos = 0; pos < 36; ++pos)
      for (int c = 0; c < 3; ++c) S += fabs(W1R[og * 864 + pos * 24 + c * 8 + oj]);
    EPS[oc] = (float)(S * (108.0 * u24 * 6.0) * 0.25);
  } else if (oc < 96) {
    int o = oc - 32, og = o >> 4, oj = o & 15;
    double S = 0.0;
    for (int c = 0; c < 32; ++c)
      for (int pos = 0; pos < 36; ++pos) S += fabs(W2R[og * 18432 + c * 576 + pos * 16 + oj]);
    EPS[oc] = (float)(S * (1152.0 * u24 * 6.0) * 0.25);
  }
}

// --- spike gen: per-pixel 3-bit channel codes [t,b,1024] bytes ------------
__global__ __launch_bounds__(256) void gen_spikes(const float* __restrict__ x,
                                                  unsigned char* __restrict__ spk0c) {
  int g = blockIdx.x * 256 + threadIdx.x;
  if (g >= NSTEPS * NB * 1024) return;
  int tb = g >> 10, pix = g & 1023;
  int b = tb & 63;
  unsigned code = 0;
  #pragma unroll
  for (int c = 0; c < 3; ++c) {
    uint32_t i = (uint32_t)((tb * 3 + c) * 1024 + pix);
    uint32_t x0 = 0u, x1 = i;
    threefry2x32(0u, 1u, x0, x1);
    uint32_t bits = x0 ^ x1;
    float u = __uint_as_float((bits >> 9) | 0x3f800000u) - 1.0f;
    float xv = x[(b * 3 + c) * 1024 + pix];
    code |= (u < 2.0f * xv) ? (1u << c) : 0u;
  }
  spk0c[g] = (unsigned char)code;
}

// --- conv1+pool f32, 4 t per thread, LDS weights, dense flags -------------
__global__ __launch_bounds__(256, 4) void conv1_f32(const unsigned char* __restrict__ spk0c,
                                                    const float* __restrict__ W1F,
                                                    const float* __restrict__ EPS,
                                                    unsigned char* __restrict__ A1,
                                                    unsigned char* __restrict__ B1,
                                                    unsigned char* __restrict__ F1) {
  const int og  = blockIdx.y;
  const int tid = threadIdx.x;
  const int id0 = blockIdx.x * 256;
  const int id  = id0 + tid;
  const int tb0 = id0 / 196;
  __shared__ unsigned char sC[3][4][1024];
  __shared__ float sW[864];

  if (tid < 216) ((float4*)sW)[tid] = ((const float4*)(W1F + og * 864))[tid];
  #pragma unroll
  for (int k = 0; k < 3; ++k) {
    int idx = tid + k * 256;
    int fi = idx >> 6, lane = idx & 63;
    int seg = fi >> 2, tt = fi & 3;
    int tb = tb0 + seg; if (tb > 1599) tb = 1599;
    int b = tb & 63, tq = tb >> 6;
    ((uint4*)sC)[idx] =
        ((const uint4*)(spk0c + (size_t)((tq * 4 + tt) * NB + b) * 1024))[lane];
  }
  __syncthreads();

  const int tb  = id / 196;
  const int p   = id - tb * 196;
  const int seg = tb - tb0;
  const int b = tb & 63, tq = tb >> 6;
  const int oh = p / 14, ow = p - oh * 14;
  const unsigned char* base = &sC[seg][0][(2 * oh) * 32 + 2 * ow];

  f32x2 acc[16];
  #pragma unroll
  for (int i = 0; i < 16; ++i) acc[i] = (f32x2)(0.0f);

  #pragma unroll
  for (int iy = 0; iy < 6; ++iy) {
    #pragma unroll
    for (int ix = 0; ix < 6; ++ix) {
      const int pos = iy * 6 + ix, off = iy * 32 + ix;
      unsigned c0 = base[0 * 1024 + off];
      unsigned c1 = base[1 * 1024 + off];
      unsigned c2 = base[2 * 1024 + off];
      unsigned c3 = base[3 * 1024 + off];
      #pragma unroll
      for (int c = 0; c < 3; ++c) {
        float f0 = (float)((c0 >> c) & 1u), f1 = (float)((c1 >> c) & 1u);
        float f2 = (float)((c2 >> c) & 1u), f3 = (float)((c3 >> c) & 1u);
        f32x2 b0 = {f0, f0}, b1 = {f1, f1}, b2 = {f2, f2}, b3 = {f3, f3};
        const f32x2* wp = (const f32x2*)(&sW[pos * 24 + c * 8]);
        #pragma unroll
        for (int ojp = 0; ojp < 4; ++ojp) {
          f32x2 w = wp[ojp];
          acc[0 + ojp]  = __builtin_elementwise_fma(b0, w, acc[0 + ojp]);
          acc[4 + ojp]  = __builtin_elementwise_fma(b1, w, acc[4 + ojp]);
          acc[8 + ojp]  = __builtin_elementwise_fma(b2, w, acc[8 + ojp]);
          acc[12 + ojp] = __builtin_elementwise_fma(b3, w, acc[12 + ojp]);
        }
      }
    }
  }

  // clean scalar extraction — acc never touched after this
  float cur[32];
  #pragma unroll
  for (int tt = 0; tt < 4; ++tt)
    #pragma unroll
    for (int ojp = 0; ojp < 4; ++ojp) {
      f32x2 v = acc[tt * 4 + ojp];
      cur[tt * 8 + 2 * ojp]     = v.x * 0.25f;
      cur[tt * 8 + 2 * ojp + 1] = v.y * 0.25f;
    }

  float eps[8];
  #pragma unroll
  for (int oj = 0; oj < 8; ++oj) eps[oj] = EPS[og * 8 + oj];

  #pragma unroll
  for (int tt = 0; tt < 4; ++tt) {
    unsigned ab = 0, bb = 0, fb = 0;
    #pragma unroll
    for (int oj = 0; oj < 8; ++oj) {
      float c = cur[tt * 8 + oj];
      if (c > 1.0f) ab |= 1u << oj;
      if (c > 2.0f) bb |= 1u << oj;
      if (fabsf(c - 1.0f) <= eps[oj] || fabsf(c - 2.0f) <= eps[oj]) fb |= 1u << oj;
    }
    const int t = tq * 4 + tt;
    size_t idx = ((size_t)(t * NB + b) * 196 + p) * 4 + og;
    A1[idx] = (unsigned char)ab;
    B1[idx] = (unsigned char)bb;
    F1[idx] = (unsigned char)fb;
  }
}

// --- fixup 1: scan F1, exact f64 recompute, patch A1/B1 bits --------------
__global__ __launch_bounds__(256) void fix1(const uint32_t* __restrict__ F1w,
                                            const unsigned char* __restrict__ spk0c,
                                            const double* __restrict__ W1R,
                                            unsigned char* __restrict__ A1,
                                            unsigned char* __restrict__ B1) {
  int wi = blockIdx.x * 256 + threadIdx.x;
  if (wi >= 1254400) return;  // 5,017,600 / 4
  uint32_t w = F1w[wi];
  if (!w) return;
  for (int k = 0; k < 4; ++k) {
    unsigned fb = (w >> (k * 8)) & 0xffu;
    if (!fb) continue;
    int byteIdx = wi * 4 + k;
    int og = byteIdx & 3, x = byteIdx >> 2;
    int tb = x / 196, p = x % 196;
    int oh = p / 14, ow = p % 14;
    const unsigned char* F = spk0c + (size_t)tb * 1024;
    unsigned a = A1[byteIdx], bbyte = B1[byteIdx];
    for (int oj = 0; oj < 8; ++oj) {
      if (!((fb >> oj) & 1u)) continue;
      double acc = 0.0;
      for (int iy = 0; iy < 6; ++iy)
        for (int ix = 0; ix < 6; ++ix) {
          unsigned code = F[(2 * oh + iy) * 32 + 2 * ow + ix];
          for (int c = 0; c < 3; ++c) {
            double bd = (double)((code >> c) & 1u);
            acc = fma(bd, W1R[og * 864 + (iy * 6 + ix) * 24 + c * 8 + oj], acc);
          }
        }
      float cur = (float)(acc * 0.25);
      unsigned m = 1u << oj;
      a = (cur > 1.0f) ? (a | m) : (a & ~m);
      bbyte = (cur > 2.0f) ? (bbyte | m) : (bbyte & ~m);
    }
    A1[byteIdx] = (unsigned char)a;
    B1[byteIdx] = (unsigned char)bbyte;
  }
}

// --- LIF1 scan: batched register prefetch --------------------------------
__global__ __launch_bounds__(64) void scan1(const uint32_t* __restrict__ A1w,
                                            const uint32_t* __restrict__ B1w,
                                            uint32_t* __restrict__ mask1) {
  int chain = blockIdx.x * 64 + threadIdx.x;
  if (chain >= NB * 196) return;
  int b = chain / 196, p = chain % 196;
  const size_t stride = (size_t)NB * 196;
  size_t base = (size_t)b * 196 + p;
  uint32_t prev = 0;
  #pragma unroll
  for (int seg = 0; seg < 4; ++seg) {
    uint32_t Abuf[25], Bbuf[25];
    size_t sb = base + (size_t)(seg * 25) * stride;
    #pragma unroll
    for (int i = 0; i < 25; ++i) {
      Abuf[i] = A1w[sb + i * stride];
      Bbuf[i] = B1w[sb + i * stride];
    }
    #pragma unroll
    for (int i = 0; i < 25; ++i) {
      uint32_t s = (Abuf[i] & ~prev) | (Bbuf[i] & prev);
      mask1[sb + i * stride] = s;
      prev = s;
    }
  }
}

// --- conv2+pool f32: 10 t per block, 16 oc, skip, dense flags -------------
__global__ __launch_bounds__(256, 4) void conv2_f32(const uint32_t* __restrict__ mask1,
                                                    const float* __restrict__ W2F,
                                                    const float* __restrict__ EPS,
                                                    unsigned char* __restrict__ A2,
                                                    unsigned char* __restrict__ B2,
                                                    unsigned char* __restrict__ F2) {
  const int tc = blockIdx.x;   // 0..9
  const int b  = blockIdx.y;   // 0..63
  const int og = blockIdx.z;   // 0..3 -> oc og*16..+15
  const int t0 = tc * 10;
  __shared__ uint32_t sM[10 * 196];
  const int tid = threadIdx.x;

  for (int e = tid; e < 490; e += 256) {
    int fr = e / 49, w4 = e % 49;
    ((uint4*)sM)[e] =
        *((const uint4*)(mask1 + (size_t)((t0 + fr) * NB + b) * 196) + w4);
  }
  __syncthreads();

  const int lane = tid & 63;
  int thLo = (tid & ~63) / 25;
  int thHi = ((tid & ~63) + 63) / 25; if (thHi > 9) thHi = 9;
  uint32_t ca = 0;
  for (int e = thLo * 196 + lane; e < (thHi + 1) * 196; e += 64) ca |= sM[e];
  #pragma unroll
  for (int off = 32; off > 0; off >>= 1) ca |= __shfl_xor(ca, off);
  const uint32_t skipOr = ca;

  const int th = tid / 25, p = tid - th * 25;
  if (tid < 250) {
    const int oh = p / 5, ow = p - oh * 5;
    uint32_t m[36];
    const uint32_t* basep = &sM[th * 196 + (2 * oh) * 14 + 2 * ow];
    #pragma unroll
    for (int iy = 0; iy < 6; ++iy)
      #pragma unroll
      for (int ix = 0; ix < 6; ++ix) m[iy * 6 + ix] = basep[iy * 14 + ix];

    f32x2 acc[8];
    #pragma unroll
    for (int i = 0; i < 8; ++i) acc[i] = (f32x2)(0.0f);
    const float* Wb = W2F + (size_t)og * 18432;
    for (int c = 0; c < 32; ++c) {
      if (!((skipOr >> c) & 1u)) continue;
      const f32x2* wc = (const f32x2*)(Wb + c * 576);
      #pragma unroll
      for (int pos = 0; pos < 36; ++pos) {
        float bf = (float)((m[pos] >> c) & 1u);
        f32x2 bv = {bf, bf};
        const f32x2* wp = wc + pos * 8;
        #pragma unroll
        for (int ojp = 0; ojp < 8; ++ojp)
          acc[ojp] = __builtin_elementwise_fma(bv, wp[ojp], acc[ojp]);
      }
    }

    // clean scalar extraction — acc never touched after this
    float cur[16];
    #pragma unroll
    for (int i = 0; i < 8; ++i) {
      f32x2 v = acc[i];
      cur[2 * i]     = v.x * 0.25f;
      cur[2 * i + 1] = v.y * 0.25f;
    }

    unsigned ab0 = 0, ab1 = 0, bb0 = 0, bb1 = 0, fb0 = 0, fb1 = 0;
    #pragma unroll
    for (int oj = 0; oj < 8; ++oj) {
      float cl = cur[oj], e0 = EPS[32 + og * 16 + oj];
      if (cl > 1.0f) ab0 |= 1u << oj;
      if (cl > 2.0f) bb0 |= 1u << oj;
      if (fabsf(cl - 1.0f) <= e0 || fabsf(cl - 2.0f) <= e0) fb0 |= 1u << oj;
      float ch = cur[8 + oj], e1 = EPS[32 + og * 16 + 8 + oj];
      if (ch > 1.0f) ab1 |= 1u << oj;
      if (ch > 2.0f) bb1 |= 1u << oj;
      if (fabsf(ch - 1.0f) <= e1 || fabsf(ch - 2.0f) <= e1) fb1 |= 1u << oj;
    }
    const int t = t0 + th;
    size_t idx = ((size_t)(t * NB + b) * 25 + p) * 8 + og * 2;
    A2[idx] = (unsigned char)ab0; A2[idx + 1] = (unsigned char)ab1;
    B2[idx] = (unsigned char)bb0; B2[idx + 1] = (unsigned char)bb1;
    F2[idx] = (unsigned char)fb0; F2[idx + 1] = (unsigned char)fb1;
  }
}

// --- fixup 2: scan F2, exact f64 recompute, patch A2/B2 bits --------------
__global__ __launch_bounds__(256) void fix2(const uint32_t* __restrict__ F2w,
                                            const uint32_t* __restrict__ mask1,
                                            const double* __restrict__ W2R,
                                            unsigned char* __restrict__ A2,
                                            unsigned char* __restrict__ B2) {
  int wi = blockIdx.x * 256 + threadIdx.x;
  if (wi >= 320000) return;  // 1,280,000 / 4
  uint32_t w = F2w[wi];
  if (!w) return;
  for (int k = 0; k < 4; ++k) {
    unsigned fb = (w >> (k * 8)) & 0xffu;
    if (!fb) continue;
    int byteIdx = wi * 4 + k;
    int og2 = byteIdx & 7, og = og2 >> 1, h = og2 & 1;
    int x = byteIdx >> 3;
    int tb = x / 25, p = x % 25;
    int oh = p / 5, ow = p % 5;
    const uint32_t* M = mask1 + (size_t)tb * 196;
    unsigned a = A2[byteIdx], bbyte = B2[byteIdx];
    for (int bit = 0; bit < 8; ++bit) {
      if (!((fb >> bit) & 1u)) continue;
      int oj = h * 8 + bit;
      double acc = 0.0;
      for (int c = 0; c < 32; ++c)
        for (int iy = 0; iy < 6; ++iy)
          for (int ix = 0; ix < 6; ++ix) {
            uint32_t mm = M[(2 * oh + iy) * 14 + 2 * ow + ix];
            double bd = (double)((mm >> c) & 1u);
            acc = fma(bd, W2R[og * 18432 + c * 576 + (iy * 6 + ix) * 16 + oj], acc);
          }
      float cur = (float)(acc * 0.25);
      unsigned m = 1u << bit;
      a = (cur > 1.0f) ? (a | m) : (a & ~m);
      bbyte = (cur > 2.0f) ? (bbyte | m) : (bbyte & ~m);
    }
    A2[byteIdx] = (unsigned char)a;
    B2[byteIdx] = (unsigned char)bbyte;
  }
}

// --- LIF2 scan ------------------------------------------------------------
__global__ __launch_bounds__(64) void scan2(const uint64_t* __restrict__ A2q,
                                            const uint64_t* __restrict__ B2q,
                                            uint64_t* __restrict__ mask2) {
  int chain = blockIdx.x * 64 + threadIdx.x;
  if (chain >= NB * 25) return;
  int b = chain / 25, p = chain % 25;
  const size_t stride = (size_t)NB * 25;
  size_t base = (size_t)b * 25 + p;
  uint64_t prev = 0;
  #pragma unroll
  for (int seg = 0; seg < 4; ++seg) {
    uint64_t Abuf[25], Bbuf[25];
    size_t sb = base + (size_t)(seg * 25) * stride;
    #pragma unroll
    for (int i = 0; i < 25; ++i) {
      Abuf[i] = A2q[sb + i * stride];
      Bbuf[i] = B2q[sb + i * stride];
    }
    #pragma unroll
    for (int i = 0; i < 25; ++i) {
      uint64_t s = (Abuf[i] & ~prev) | (Bbuf[i] & prev);
      mask2[sb + i * stride] = s;
      prev = s;
    }
  }
}

// --- FC: thread = (t,b,o,s); s owns 8 oc; shfl_xor reduce over 8 lanes ----
__global__ __launch_bounds__(256) void fc_kernel(const uint64_t* __restrict__ mask2,
                                                 const float* __restrict__ W2,
                                                 float* __restrict__ cur3) {
  int gid = blockIdx.x * 256 + threadIdx.x;
  if (gid >= NSTEPS * NB * 80) return;
  int tb = gid / 80, r = gid % 80;
  int o = r >> 3, s = r & 7;
  const uint64_t* m = mask2 + (size_t)tb * 25;
  const float* w = W2 + o * 1600 + s * 200;  // k = oc*25+p, oc = s*8..s*8+7

  uint64_t mw[25];
  #pragma unroll
  for (int p = 0; p < 25; ++p) mw[p] = m[p];

  const int oc0 = s * 8;
  double acc0 = 0.0, acc1 = 0.0;
  #pragma unroll
  for (int j = 0; j < 8; ++j) {
    const float* wj = w + j * 25;
    double a = 0.0;
    #pragma unroll
    for (int p = 0; p < 25; ++p) {
      double bd = (double)((mw[p] >> (oc0 + j)) & 1ull);
      a = fma(bd, (double)wj[p], a);
    }
    if (j & 1) acc1 += a; else acc0 += a;
  }
  double acc = acc0 + acc1;
  acc += __shfl_xor(acc, 4);
  acc += __shfl_xor(acc, 2);
  acc += __shfl_xor(acc, 1);
  if (s == 0) cur3[tb * 10 + o] = (float)acc;
}

// --- LIF3: batch-prefetch scan; out spikes [100,640] then mem [100,640] ---
__global__ __launch_bounds__(64) void lif3_kernel(const float* __restrict__ cur3,
                                                  float* __restrict__ out) {
  int bo = blockIdx.x * 64 + threadIdx.x;
  if (bo >= NB * 10) return;
  float prev = 0.0f;
  #pragma unroll
  for (int seg = 0; seg < 4; ++seg) {
    float cbuf[25];
    #pragma unroll
    for (int i = 0; i < 25; ++i) cbuf[i] = cur3[(seg * 25 + i) * 640 + bo];
    #pragma unroll
    for (int i = 0; i < 25; ++i) {
      int t = seg * 25 + i;
      float mem = cbuf[i] - prev;
      bool s = mem > 1.0f;
      out[t * 640 + bo] = s ? 1.0f : 0.0f;
      out[NSTEPS * 640 + t * 640 + bo] = mem;
      prev = s ? 1.0f : 0.0f;
    }
  }
}

extern "C" void kernel_launch(void* const* d_in, const int* in_sizes, int n_in,
                              void* d_out, int out_size, void* d_ws, size_t ws_size,
                              hipStream_t stream) {
  const float* x    = (const float*)d_in[0];
  const float* W_in = (const float*)d_in[1];
  const float* W_h1 = (const float*)d_in[2];
  const float* W_h2 = (const float*)d_in[3];
  float* out = (float*)d_out;

  unsigned char* ws = (unsigned char*)d_ws;
  double*        W1R   = (double*)(ws + 0);           //     27,648
  double*        W2R   = (double*)(ws + 27648);       //    589,824
  float*         W1F   = (float*)(ws + 617472);       //     13,824
  float*         W2F   = (float*)(ws + 631296);       //    294,912
  float*         EPS   = (float*)(ws + 926208);       //        384 (pad 128)
  unsigned char* spk0c = ws + 926720;                 //  6,553,600
  unsigned char* A1    = ws + 7480320;                //  5,017,600
  unsigned char* B1    = ws + 12497920;               //  5,017,600
  unsigned char* F1    = ws + 17515520;               //  5,017,600
  uint32_t*      mask1 = (uint32_t*)(ws + 22533120);  //  5,017,600
  unsigned char* A2    = ws + 27550720;               //  1,280,000
  unsigned char* B2    = ws + 28830720;               //  1,280,000
  unsigned char* F2    = ws + 30110720;               //  1,280,000
  uint64_t*      mask2 = (uint64_t*)(ws + 31390720);  //  1,280,000
  float*         cur3  = (float*)(ws + 32670720);     //    256,000 (end ~33 MB)

  weff_all<<<302, 256, 0, stream>>>(W_in, W_h1, W1R, W2R, W1F, W2F);
  eps_kernel<<<1, 128, 0, stream>>>(W1R, W2R, EPS);
  gen_spikes<<<NSTEPS * NB * 4, 256, 0, stream>>>(x, spk0c);
  conv1_f32<<<dim3(1225, 4), 256, 0, stream>>>(spk0c, W1F, EPS, A1, B1, F1);
  fix1<<<(1254400 + 255) / 256, 256, 0, stream>>>((const uint32_t*)F1, spk0c, W1R, A1, B1);
  scan1<<<(NB * 196 + 63) / 64, 64, 0, stream>>>((const uint32_t*)A1,
                                                 (const uint32_t*)B1, mask1);
  conv2_f32<<<dim3(10, NB, 4), 256, 0, stream>>>(mask1, W2F, EPS, A2, B2, F2);
  fix2<<<(320000 + 255) / 256, 256, 0, stream>>>((const uint32_t*)F2, mask1, W2R, A2, B2);
  scan2<<<(NB * 25 + 63) / 64, 64, 0, stream>>>((const uint64_t*)A2,
                                                (const uint64_t*)B2, mask2);
  fc_kernel<<<(NSTEPS * NB * 80 + 255) / 256, 256, 0, stream>>>(mask2, W_h2, cur3);
  lif3_kernel<<<10, 64, 0, stream>>>(cur3, out);
}

// Round 10
// 462.881 us; speedup vs baseline: 6.7897x; 1.0318x over previous
//
#include <hip/hip_runtime.h>
#include <stdint.h>

// ---------------------------------------------------------------------------
// Conv-SNN, 100 steps, B=64, BETA=0.
// Round 10: conv2 -> MFMA (bf16 hi/lo split, fp32 acc).
//  - per (t,b): C[25(pad32) x 64] = S[25 x 1152] * W[1152 x 64], K pos-major.
//  - A frags built in registers from mask1 bits (0/1 exact in bf16).
//  - B frags pre-expanded to fragment-layout bf16 hi/lo pairs (wprep2).
//  - w = hi + lo: residual |w|*2^-18; total error < existing eps bound, so
//    the dense-flag + f64 fixup machinery keeps bits exact (unchanged).
//  - epilogue regroups D layout via per-wave LDS tile into A2/B2/F2 bytes
//    (consumers scan2/fix2/fc unchanged).
// conv1 and all other kernels unchanged from round 9 (absmax 0.0 lineage).
// ---------------------------------------------------------------------------

#define NSTEPS 100
#define NB 64

typedef float f32x2 __attribute__((ext_vector_type(2)));
typedef short bf16x8 __attribute__((ext_vector_type(8)));
typedef float f32x4 __attribute__((ext_vector_type(4)));

__device__ __forceinline__ uint32_t rotl32(uint32_t v, uint32_t r) {
  return (v << r) | (v >> (32u - r));
}

__device__ __forceinline__ void threefry2x32(uint32_t k0, uint32_t k1,
                                             uint32_t& x0, uint32_t& x1) {
  uint32_t k2 = k0 ^ k1 ^ 0x1BD11BDAu;
  x0 += k0; x1 += k1;
#define TF_R(r) { x0 += x1; x1 = rotl32(x1, r); x1 ^= x0; }
  TF_R(13u) TF_R(15u) TF_R(26u) TF_R(6u)
  x0 += k1; x1 += k2 + 1u;
  TF_R(17u) TF_R(29u) TF_R(16u) TF_R(24u)
  x0 += k2; x1 += k0 + 2u;
  TF_R(13u) TF_R(15u) TF_R(26u) TF_R(6u)
  x0 += k0; x1 += k1 + 3u;
  TF_R(17u) TF_R(29u) TF_R(16u) TF_R(24u)
  x0 += k1; x1 += k2 + 4u;
  TF_R(13u) TF_R(15u) TF_R(26u) TF_R(6u)
  x0 += k2; x1 += k0 + 5u;
#undef TF_R
}

__device__ __forceinline__ double fold_pool_w(const float* W, int base, int pos) {
  int iy = pos / 6, ix = pos % 6;
  double w = 0.0;
  for (int dy = 0; dy < 2; ++dy) {
    int ky = iy - dy; if (ky < 0 || ky > 4) continue;
    for (int dx = 0; dx < 2; ++dx) {
      int kx = ix - dx; if (kx < 0 || kx > 4) continue;
      w += (double)W[base + ky * 5 + kx];
    }
  }
  return w;
}

__device__ __forceinline__ uint16_t f2bf(float x) {  // RNE bf16
  uint32_t u = __float_as_uint(x);
  uint32_t r = (u + 0x7fffu + ((u >> 16) & 1u)) >> 16;
  return (uint16_t)r;
}

// Folded-pool weights, f64 masters + f32 conv1 copy.
// W1R/W1F: [og4][pos36][c3][oj8]   (oc = og*8+oj)
// W2R:     [og4][c32][pos36][oj16] (oc = og*16+oj)  (eps + fix2)
__global__ __launch_bounds__(256) void weff_all(const float* __restrict__ W_in,
                                                const float* __restrict__ W_h1,
                                                double* __restrict__ W1R,
                                                double* __restrict__ W2R,
                                                float* __restrict__ W1F) {
  int e = blockIdx.x * 256 + threadIdx.x;
  if (e < 3456) {
    int oj = e & 7, c = (e >> 3) % 3, pos = ((e >> 3) / 3) % 36, og = (e >> 3) / 108;
    int oc = og * 8 + oj;
    double w = fold_pool_w(W_in, (oc * 3 + c) * 25, pos);
    W1R[e] = w; W1F[e] = (float)w;
  } else if (e < 3456 + 73728) {
    int e2 = e - 3456;
    int oj = e2 & 15, pos = (e2 >> 4) % 36, c = ((e2 >> 4) / 36) % 32, og = e2 / 18432;
    int oc = og * 16 + oj;
    W2R[e2] = fold_pool_w(W_h1, (oc * 32 + c) * 25, pos);
  }
}

// conv2 MFMA B-frag weights: WB[hl2][pos36][nt4][lane64][j8] bf16
// element: oc = nt*16 + (lane&15), c = (lane>>4)*8 + j, value hi/lo of fold.
__global__ __launch_bounds__(256) void wprep2(const float* __restrict__ W_h1,
                                              uint16_t* __restrict__ WB) {
  int e = blockIdx.x * 256 + threadIdx.x;  // 73728 = 36*4*64*8
  if (e >= 36 * 4 * 64 * 8) return;
  int j = e & 7, lane = (e >> 3) & 63, nt = (e >> 9) & 3, pos = e >> 11;
  int oc = nt * 16 + (lane & 15);
  int c  = (lane >> 4) * 8 + j;
  double w = fold_pool_w(W_h1, (oc * 32 + c) * 25, pos);
  uint16_t hi = f2bf((float)w);
  float hif = __uint_as_float(((uint32_t)hi) << 16);
  uint16_t lo = f2bf((float)(w - (double)hif));
  WB[e] = hi;                    // hl=0 plane
  WB[73728 + e] = lo;            // hl=1 plane
}

// EPS[0..31]: conv1 per-oc flag radius; EPS[32..95]: conv2 per-oc.
__global__ __launch_bounds__(128) void eps_kernel(const double* __restrict__ W1R,
                                                  const double* __restrict__ W2R,
                                                  float* __restrict__ EPS) {
  int oc = blockIdx.x * 128 + threadIdx.x;
  const double u24 = 5.9604644775390625e-08;
  if (oc < 32) {
    int og = oc >> 3, oj = oc & 7;
    double S = 0.0;
    for (int pos = 0; pos < 36; ++pos)
      for (int c = 0; c < 3; ++c) S += fabs(W1R[og * 864 + pos * 24 + c * 8 + oj]);
    EPS[oc] = (float)(S * (108.0 * u24 * 6.0) * 0.25);
  } else if (oc < 96) {
    int o = oc - 32, og = o >> 4, oj = o & 15;
    double S = 0.0;
    for (int c = 0; c < 32; ++c)
      for (int pos = 0; pos < 36; ++pos) S += fabs(W2R[og * 18432 + c * 576 + pos * 16 + oj]);
    EPS[oc] = (float)(S * (1152.0 * u24 * 6.0) * 0.25);
  }
}

// --- spike gen: per-pixel 3-bit channel codes [t,b,1024] bytes ------------
__global__ __launch_bounds__(256) void gen_spikes(const float* __restrict__ x,
                                                  unsigned char* __restrict__ spk0c) {
  int g = blockIdx.x * 256 + threadIdx.x;
  if (g >= NSTEPS * NB * 1024) return;
  int tb = g >> 10, pix = g & 1023;
  int b = tb & 63;
  unsigned code = 0;
  #pragma unroll
  for (int c = 0; c < 3; ++c) {
    uint32_t i = (uint32_t)((tb * 3 + c) * 1024 + pix);
    uint32_t x0 = 0u, x1 = i;
    threefry2x32(0u, 1u, x0, x1);
    uint32_t bits = x0 ^ x1;
    float u = __uint_as_float((bits >> 9) | 0x3f800000u) - 1.0f;
    float xv = x[(b * 3 + c) * 1024 + pix];
    code |= (u < 2.0f * xv) ? (1u << c) : 0u;
  }
  spk0c[g] = (unsigned char)code;
}

// --- conv1+pool f32, 4 t per thread, LDS weights, dense flags -------------
__global__ __launch_bounds__(256, 4) void conv1_f32(const unsigned char* __restrict__ spk0c,
                                                    const float* __restrict__ W1F,
                                                    const float* __restrict__ EPS,
                                                    unsigned char* __restrict__ A1,
                                                    unsigned char* __restrict__ B1,
                                                    unsigned char* __restrict__ F1) {
  const int og  = blockIdx.y;
  const int tid = threadIdx.x;
  const int id0 = blockIdx.x * 256;
  const int id  = id0 + tid;
  const int tb0 = id0 / 196;
  __shared__ unsigned char sC[3][4][1024];
  __shared__ float sW[864];

  if (tid < 216) ((float4*)sW)[tid] = ((const float4*)(W1F + og * 864))[tid];
  #pragma unroll
  for (int k = 0; k < 3; ++k) {
    int idx = tid + k * 256;
    int fi = idx >> 6, lane = idx & 63;
    int seg = fi >> 2, tt = fi & 3;
    int tb = tb0 + seg; if (tb > 1599) tb = 1599;
    int b = tb & 63, tq = tb >> 6;
    ((uint4*)sC)[idx] =
        ((const uint4*)(spk0c + (size_t)((tq * 4 + tt) * NB + b) * 1024))[lane];
  }
  __syncthreads();

  const int tb  = id / 196;
  const int p   = id - tb * 196;
  const int seg = tb - tb0;
  const int b = tb & 63, tq = tb >> 6;
  const int oh = p / 14, ow = p - oh * 14;
  const unsigned char* base = &sC[seg][0][(2 * oh) * 32 + 2 * ow];

  f32x2 acc[16];
  #pragma unroll
  for (int i = 0; i < 16; ++i) acc[i] = (f32x2)(0.0f);

  #pragma unroll
  for (int iy = 0; iy < 6; ++iy) {
    #pragma unroll
    for (int ix = 0; ix < 6; ++ix) {
      const int pos = iy * 6 + ix, off = iy * 32 + ix;
      unsigned c0 = base[0 * 1024 + off];
      unsigned c1 = base[1 * 1024 + off];
      unsigned c2 = base[2 * 1024 + off];
      unsigned c3 = base[3 * 1024 + off];
      #pragma unroll
      for (int c = 0; c < 3; ++c) {
        float f0 = (float)((c0 >> c) & 1u), f1 = (float)((c1 >> c) & 1u);
        float f2 = (float)((c2 >> c) & 1u), f3 = (float)((c3 >> c) & 1u);
        f32x2 b0 = {f0, f0}, b1 = {f1, f1}, b2 = {f2, f2}, b3 = {f3, f3};
        const f32x2* wp = (const f32x2*)(&sW[pos * 24 + c * 8]);
        #pragma unroll
        for (int ojp = 0; ojp < 4; ++ojp) {
          f32x2 w = wp[ojp];
          acc[0 + ojp]  = __builtin_elementwise_fma(b0, w, acc[0 + ojp]);
          acc[4 + ojp]  = __builtin_elementwise_fma(b1, w, acc[4 + ojp]);
          acc[8 + ojp]  = __builtin_elementwise_fma(b2, w, acc[8 + ojp]);
          acc[12 + ojp] = __builtin_elementwise_fma(b3, w, acc[12 + ojp]);
        }
      }
    }
  }

  float cur[32];
  #pragma unroll
  for (int tt = 0; tt < 4; ++tt)
    #pragma unroll
    for (int ojp = 0; ojp < 4; ++ojp) {
      f32x2 v = acc[tt * 4 + ojp];
      cur[tt * 8 + 2 * ojp]     = v.x * 0.25f;
      cur[tt * 8 + 2 * ojp + 1] = v.y * 0.25f;
    }

  float eps[8];
  #pragma unroll
  for (int oj = 0; oj < 8; ++oj) eps[oj] = EPS[og * 8 + oj];

  #pragma unroll
  for (int tt = 0; tt < 4; ++tt) {
    unsigned ab = 0, bb = 0, fb = 0;
    #pragma unroll
    for (int oj = 0; oj < 8; ++oj) {
      float c = cur[tt * 8 + oj];
      if (c > 1.0f) ab |= 1u << oj;
      if (c > 2.0f) bb |= 1u << oj;
      if (fabsf(c - 1.0f) <= eps[oj] || fabsf(c - 2.0f) <= eps[oj]) fb |= 1u << oj;
    }
    const int t = tq * 4 + tt;
    size_t idx = ((size_t)(t * NB + b) * 196 + p) * 4 + og;
    A1[idx] = (unsigned char)ab;
    B1[idx] = (unsigned char)bb;
    F1[idx] = (unsigned char)fb;
  }
}

// --- fixup 1: scan F1, exact f64 recompute, patch A1/B1 bits --------------
__global__ __launch_bounds__(256) void fix1(const uint32_t* __restrict__ F1w,
                                            const unsigned char* __restrict__ spk0c,
                                            const double* __restrict__ W1R,
                                            unsigned char* __restrict__ A1,
                                            unsigned char* __restrict__ B1) {
  int wi = blockIdx.x * 256 + threadIdx.x;
  if (wi >= 1254400) return;
  uint32_t w = F1w[wi];
  if (!w) return;
  for (int k = 0; k < 4; ++k) {
    unsigned fb = (w >> (k * 8)) & 0xffu;
    if (!fb) continue;
    int byteIdx = wi * 4 + k;
    int og = byteIdx & 3, x = byteIdx >> 2;
    int tb = x / 196, p = x % 196;
    int oh = p / 14, ow = p % 14;
    const unsigned char* F = spk0c + (size_t)tb * 1024;
    unsigned a = A1[byteIdx], bbyte = B1[byteIdx];
    for (int oj = 0; oj < 8; ++oj) {
      if (!((fb >> oj) & 1u)) continue;
      double acc = 0.0;
      for (int iy = 0; iy < 6; ++iy)
        for (int ix = 0; ix < 6; ++ix) {
          unsigned code = F[(2 * oh + iy) * 32 + 2 * ow + ix];
          for (int c = 0; c < 3; ++c) {
            double bd = (double)((code >> c) & 1u);
            acc = fma(bd, W1R[og * 864 + (iy * 6 + ix) * 24 + c * 8 + oj], acc);
          }
        }
      float cur = (float)(acc * 0.25);
      unsigned m = 1u << oj;
      a = (cur > 1.0f) ? (a | m) : (a & ~m);
      bbyte = (cur > 2.0f) ? (bbyte | m) : (bbyte & ~m);
    }
    A1[byteIdx] = (unsigned char)a;
    B1[byteIdx] = (unsigned char)bbyte;
  }
}

// --- LIF1 scan: batched register prefetch --------------------------------
__global__ __launch_bounds__(64) void scan1(const uint32_t* __restrict__ A1w,
                                            const uint32_t* __restrict__ B1w,
                                            uint32_t* __restrict__ mask1) {
  int chain = blockIdx.x * 64 + threadIdx.x;
  if (chain >= NB * 196) return;
  int b = chain / 196, p = chain % 196;
  const size_t stride = (size_t)NB * 196;
  size_t base = (size_t)b * 196 + p;
  uint32_t prev = 0;
  #pragma unroll
  for (int seg = 0; seg < 4; ++seg) {
    uint32_t Abuf[25], Bbuf[25];
    size_t sb = base + (size_t)(seg * 25) * stride;
    #pragma unroll
    for (int i = 0; i < 25; ++i) {
      Abuf[i] = A1w[sb + i * stride];
      Bbuf[i] = B1w[sb + i * stride];
    }
    #pragma unroll
    for (int i = 0; i < 25; ++i) {
      uint32_t s = (Abuf[i] & ~prev) | (Bbuf[i] & prev);
      mask1[sb + i * stride] = s;
      prev = s;
    }
  }
}

// --- conv2 via MFMA: per (t,b) GEMM C[32p x 64oc], K=1152, bf16 hi/lo -----
// block = 4 waves, wave = one (t,b). A frags from mask bits (registers);
// B frags from WB (frag-layout, L2-cached). Epilogue via per-wave LDS tile.
__global__ __launch_bounds__(256, 2) void conv2_mfma(const uint32_t* __restrict__ mask1,
                                                     const uint16_t* __restrict__ WB,
                                                     const float* __restrict__ EPS,
                                                     unsigned char* __restrict__ A2,
                                                     unsigned char* __restrict__ B2,
                                                     unsigned char* __restrict__ F2) {
  __shared__ uint32_t sM[4 * 196];
  __shared__ float sCur[4][32 * 64];
  __shared__ float sEps[64];
  const int tid = threadIdx.x;
  const int wid = tid >> 6, lane = tid & 63;
  const int tb = blockIdx.x * 4 + wid;   // 0..6399

  {
    const uint32_t* src = mask1 + (size_t)tb * 196;
    for (int i = lane; i < 196; i += 64) sM[wid * 196 + i] = src[i];
  }
  if (tid < 64) sEps[tid] = EPS[32 + tid];
  __syncthreads();

  const int q  = lane >> 4;   // quad 0..3
  const int ln = lane & 15;

  const int p0 = ln;                       // mt=0 rows 0..15 (all valid)
  const int p1 = 16 + ln;                  // mt=1 rows 16..31 (valid < 25)
  const bool v1 = (p1 < 25);
  const int oh0 = p0 / 5, ow0 = p0 % 5;
  const int p1c = v1 ? p1 : 0;
  const int oh1 = p1c / 5, ow1 = p1c % 5;

  f32x4 acc[8];
  #pragma unroll
  for (int i = 0; i < 8; ++i) acc[i] = (f32x4)(0.0f);

  const uint32_t* sMw = &sM[wid * 196];

  for (int iy = 0; iy < 6; ++iy) {
    #pragma unroll
    for (int ix = 0; ix < 6; ++ix) {
      const int pos = iy * 6 + ix;
      uint32_t w0 = sMw[(2 * oh0 + iy) * 14 + 2 * ow0 + ix];
      uint32_t w1 = v1 ? sMw[(2 * oh1 + iy) * 14 + 2 * ow1 + ix] : 0u;
      uint32_t bits0 = (w0 >> (q * 8)) & 0xffu;
      uint32_t bits1 = (w1 >> (q * 8)) & 0xffu;
      union { uint32_t u[4]; bf16x8 v; } a0, a1;
      #pragma unroll
      for (int i = 0; i < 4; ++i) {
        a0.u[i] = (((bits0 >> (2 * i)) & 1u) ? 0x3F80u : 0u) |
                  (((bits0 >> (2 * i + 1)) & 1u) ? 0x3F800000u : 0u);
        a1.u[i] = (((bits1 >> (2 * i)) & 1u) ? 0x3F80u : 0u) |
                  (((bits1 >> (2 * i + 1)) & 1u) ? 0x3F800000u : 0u);
      }
      const uint16_t* bhi_base = WB + (size_t)pos * 2048 + lane * 8;
      const uint16_t* blo_base = bhi_base + 73728;
      #pragma unroll
      for (int nt = 0; nt < 4; ++nt) {
        bf16x8 bhi = *(const bf16x8*)(bhi_base + nt * 512);
        bf16x8 blo = *(const bf16x8*)(blo_base + nt * 512);
        acc[nt] = __builtin_amdgcn_mfma_f32_16x16x32_bf16(a0.v, bhi, acc[nt], 0, 0, 0);
        acc[nt] = __builtin_amdgcn_mfma_f32_16x16x32_bf16(a0.v, blo, acc[nt], 0, 0, 0);
        acc[4 + nt] = __builtin_amdgcn_mfma_f32_16x16x32_bf16(a1.v, bhi, acc[4 + nt], 0, 0, 0);
        acc[4 + nt] = __builtin_amdgcn_mfma_f32_16x16x32_bf16(a1.v, blo, acc[4 + nt], 0, 0, 0);
      }
    }
  }

  // D layout: col(oc16) = lane&15, row = q*4 + reg. Stage into per-wave tile.
  float* sc = &sCur[wid][0];
  #pragma unroll
  for (int nt = 0; nt < 4; ++nt) {
    #pragma unroll
    for (int reg = 0; reg < 4; ++reg) {
      sc[(q * 4 + reg) * 64 + nt * 16 + ln]      = acc[nt][reg];
      sc[(16 + q * 4 + reg) * 64 + nt * 16 + ln] = acc[4 + nt][reg];
    }
  }
  // same-wave LDS ops are in-order; no cross-wave sharing of sCur.
  const int p  = lane >> 1;
  const int hf = lane & 1;
  if (p < 25) {
    uint32_t aw = 0, bw = 0, fw = 0;
    #pragma unroll
    for (int jo = 0; jo < 32; ++jo) {
      int oc = hf * 32 + jo;
      float cur = sc[p * 64 + oc] * 0.25f;
      float e = sEps[oc];
      uint32_t bit = 1u << jo;
      if (cur > 1.0f) aw |= bit;
      if (cur > 2.0f) bw |= bit;
      if (fabsf(cur - 1.0f) <= e || fabsf(cur - 2.0f) <= e) fw |= bit;
    }
    uint32_t widx = (uint32_t)(tb * 25 + p) * 2 + hf;
    ((uint32_t*)A2)[widx] = aw;
    ((uint32_t*)B2)[widx] = bw;
    ((uint32_t*)F2)[widx] = fw;
  }
}

// --- fixup 2: scan F2, exact f64 recompute, patch A2/B2 bits --------------
__global__ __launch_bounds__(256) void fix2(const uint32_t* __restrict__ F2w,
                                            const uint32_t* __restrict__ mask1,
                                            const double* __restrict__ W2R,
                                            unsigned char* __restrict__ A2,
                                            unsigned char* __restrict__ B2) {
  int wi = blockIdx.x * 256 + threadIdx.x;
  if (wi >= 320000) return;
  uint32_t w = F2w[wi];
  if (!w) return;
  for (int k = 0; k < 4; ++k) {
    unsigned fb = (w >> (k * 8)) & 0xffu;
    if (!fb) continue;
    int byteIdx = wi * 4 + k;
    int og2 = byteIdx & 7, og = og2 >> 1, h = og2 & 1;
    int x = byteIdx >> 3;
    int tb = x / 25, p = x % 25;
    int oh = p / 5, ow = p % 5;
    const uint32_t* M = mask1 + (size_t)tb * 196;
    unsigned a = A2[byteIdx], bbyte = B2[byteIdx];
    for (int bit = 0; bit < 8; ++bit) {
      if (!((fb >> bit) & 1u)) continue;
      int oj = h * 8 + bit;
      double acc = 0.0;
      for (int c = 0; c < 32; ++c)
        for (int iy = 0; iy < 6; ++iy)
          for (int ix = 0; ix < 6; ++ix) {
            uint32_t mm = M[(2 * oh + iy) * 14 + 2 * ow + ix];
            double bd = (double)((mm >> c) & 1u);
            acc = fma(bd, W2R[og * 18432 + c * 576 + (iy * 6 + ix) * 16 + oj], acc);
          }
      float cur = (float)(acc * 0.25);
      unsigned m = 1u << bit;
      a = (cur > 1.0f) ? (a | m) : (a & ~m);
      bbyte = (cur > 2.0f) ? (bbyte | m) : (bbyte & ~m);
    }
    A2[byteIdx] = (unsigned char)a;
    B2[byteIdx] = (unsigned char)bbyte;
  }
}

// --- LIF2 scan ------------------------------------------------------------
__global__ __launch_bounds__(64) void scan2(const uint64_t* __restrict__ A2q,
                                            const uint64_t* __restrict__ B2q,
                                            uint64_t* __restrict__ mask2) {
  int chain = blockIdx.x * 64 + threadIdx.x;
  if (chain >= NB * 25) return;
  int b = chain / 25, p = chain % 25;
  const size_t stride = (size_t)NB * 25;
  size_t base = (size_t)b * 25 + p;
  uint64_t prev = 0;
  #pragma unroll
  for (int seg = 0; seg < 4; ++seg) {
    uint64_t Abuf[25], Bbuf[25];
    size_t sb = base + (size_t)(seg * 25) * stride;
    #pragma unroll
    for (int i = 0; i < 25; ++i) {
      Abuf[i] = A2q[sb + i * stride];
      Bbuf[i] = B2q[sb + i * stride];
    }
    #pragma unroll
    for (int i = 0; i < 25; ++i) {
      uint64_t s = (Abuf[i] & ~prev) | (Bbuf[i] & prev);
      mask2[sb + i * stride] = s;
      prev = s;
    }
  }
}

// --- FC: thread = (t,b,o,s); s owns 8 oc; shfl_xor reduce over 8 lanes ----
__global__ __launch_bounds__(256) void fc_kernel(const uint64_t* __restrict__ mask2,
                                                 const float* __restrict__ W2,
                                                 float* __restrict__ cur3) {
  int gid = blockIdx.x * 256 + threadIdx.x;
  if (gid >= NSTEPS * NB * 80) return;
  int tb = gid / 80, r = gid % 80;
  int o = r >> 3, s = r & 7;
  const uint64_t* m = mask2 + (size_t)tb * 25;
  const float* w = W2 + o * 1600 + s * 200;

  uint64_t mw[25];
  #pragma unroll
  for (int p = 0; p < 25; ++p) mw[p] = m[p];

  const int oc0 = s * 8;
  double acc0 = 0.0, acc1 = 0.0;
  #pragma unroll
  for (int j = 0; j < 8; ++j) {
    const float* wj = w + j * 25;
    double a = 0.0;
    #pragma unroll
    for (int p = 0; p < 25; ++p) {
      double bd = (double)((mw[p] >> (oc0 + j)) & 1ull);
      a = fma(bd, (double)wj[p], a);
    }
    if (j & 1) acc1 += a; else acc0 += a;
  }
  double acc = acc0 + acc1;
  acc += __shfl_xor(acc, 4);
  acc += __shfl_xor(acc, 2);
  acc += __shfl_xor(acc, 1);
  if (s == 0) cur3[tb * 10 + o] = (float)acc;
}

// --- LIF3: batch-prefetch scan; out spikes [100,640] then mem [100,640] ---
__global__ __launch_bounds__(64) void lif3_kernel(const float* __restrict__ cur3,
                                                  float* __restrict__ out) {
  int bo = blockIdx.x * 64 + threadIdx.x;
  if (bo >= NB * 10) return;
  float prev = 0.0f;
  #pragma unroll
  for (int seg = 0; seg < 4; ++seg) {
    float cbuf[25];
    #pragma unroll
    for (int i = 0; i < 25; ++i) cbuf[i] = cur3[(seg * 25 + i) * 640 + bo];
    #pragma unroll
    for (int i = 0; i < 25; ++i) {
      int t = seg * 25 + i;
      float mem = cbuf[i] - prev;
      bool s = mem > 1.0f;
      out[t * 640 + bo] = s ? 1.0f : 0.0f;
      out[NSTEPS * 640 + t * 640 + bo] = mem;
      prev = s ? 1.0f : 0.0f;
    }
  }
}

extern "C" void kernel_launch(void* const* d_in, const int* in_sizes, int n_in,
                              void* d_out, int out_size, void* d_ws, size_t ws_size,
                              hipStream_t stream) {
  const float* x    = (const float*)d_in[0];
  const float* W_in = (const float*)d_in[1];
  const float* W_h1 = (const float*)d_in[2];
  const float* W_h2 = (const float*)d_in[3];
  float* out = (float*)d_out;

  unsigned char* ws = (unsigned char*)d_ws;
  double*        W1R   = (double*)(ws + 0);           //     27,648
  double*        W2R   = (double*)(ws + 27648);       //    589,824
  float*         W1F   = (float*)(ws + 617472);       //     13,824
  uint16_t*      WB    = (uint16_t*)(ws + 631296);    //    294,912 (2x147456 bf16)
  float*         EPS   = (float*)(ws + 926208);       //        384 (pad 128)
  unsigned char* spk0c = ws + 926720;                 //  6,553,600
  unsigned char* A1    = ws + 7480320;                //  5,017,600
  unsigned char* B1    = ws + 12497920;               //  5,017,600
  unsigned char* F1    = ws + 17515520;               //  5,017,600
  uint32_t*      mask1 = (uint32_t*)(ws + 22533120);  //  5,017,600
  unsigned char* A2    = ws + 27550720;               //  1,280,000
  unsigned char* B2    = ws + 28830720;               //  1,280,000
  unsigned char* F2    = ws + 30110720;               //  1,280,000
  uint64_t*      mask2 = (uint64_t*)(ws + 31390720);  //  1,280,000
  float*         cur3  = (float*)(ws + 32670720);     //    256,000 (end ~33 MB)

  weff_all<<<302, 256, 0, stream>>>(W_in, W_h1, W1R, W2R, W1F);
  wprep2<<<288, 256, 0, stream>>>(W_h1, WB);
  eps_kernel<<<1, 128, 0, stream>>>(W1R, W2R, EPS);
  gen_spikes<<<NSTEPS * NB * 4, 256, 0, stream>>>(x, spk0c);
  conv1_f32<<<dim3(1225, 4), 256, 0, stream>>>(spk0c, W1F, EPS, A1, B1, F1);
  fix1<<<(1254400 + 255) / 256, 256, 0, stream>>>((const uint32_t*)F1, spk0c, W1R, A1, B1);
  scan1<<<(NB * 196 + 63) / 64, 64, 0, stream>>>((const uint32_t*)A1,
                                                 (const uint32_t*)B1, mask1);
  conv2_mfma<<<1600, 256, 0, stream>>>(mask1, WB, EPS, A2, B2, F2);
  fix2<<<(320000 + 255) / 256, 256, 0, stream>>>((const uint32_t*)F2, mask1, W2R, A2, B2);
  scan2<<<(NB * 25 + 63) / 64, 64, 0, stream>>>((const uint64_t*)A2,
                                                (const uint64_t*)B2, mask2);
  fc_kernel<<<(NSTEPS * NB * 80 + 255) / 256, 256, 0, stream>>>(mask2, W_h2, cur3);
  lif3_kernel<<<10, 64, 0, stream>>>(cur3, out);
}

// Round 11
// 408.953 us; speedup vs baseline: 7.6851x; 1.1319x over previous
//
#include <hip/hip_runtime.h>
#include <stdint.h>

// ---------------------------------------------------------------------------
// Conv-SNN, 100 steps, B=64, BETA=0.
// Round 11: conv1 -> MFMA too.
//  - gen_spikes emits row bitmasks (ballot): rowm[t,b][c][32 rows] u32.
//  - win_prep packs per-pixel 108-bit K-window (k = c*36+pos) -> win1 uint4.
//  - conv1_mfma: per (t,b) wave, 13 m-tiles x 2 n-tiles x 4 ksteps x hi/lo;
//    A-frag = byte extract from win1 word; epilogue via ballots (v_cmp IS
//    the 64-bit mask) -> A1/B1/F1 u32 words, layout unchanged.
//  - fix1 recomputes from rowm bits (same f64 order as always).
//  - error bound S*(216*2^-24 + 2^-18) < eps budget -> flags+f64 fixup keep
//    bits exact (same argument as conv2, HW-validated rounds 8-10).
// conv2_mfma and all downstream kernels unchanged (absmax 0.0 lineage).
// ---------------------------------------------------------------------------

#define NSTEPS 100
#define NB 64

typedef short bf16x8 __attribute__((ext_vector_type(8)));
typedef float f32x4 __attribute__((ext_vector_type(4)));

__device__ __forceinline__ uint32_t rotl32(uint32_t v, uint32_t r) {
  return (v << r) | (v >> (32u - r));
}

__device__ __forceinline__ void threefry2x32(uint32_t k0, uint32_t k1,
                                             uint32_t& x0, uint32_t& x1) {
  uint32_t k2 = k0 ^ k1 ^ 0x1BD11BDAu;
  x0 += k0; x1 += k1;
#define TF_R(r) { x0 += x1; x1 = rotl32(x1, r); x1 ^= x0; }
  TF_R(13u) TF_R(15u) TF_R(26u) TF_R(6u)
  x0 += k1; x1 += k2 + 1u;
  TF_R(17u) TF_R(29u) TF_R(16u) TF_R(24u)
  x0 += k2; x1 += k0 + 2u;
  TF_R(13u) TF_R(15u) TF_R(26u) TF_R(6u)
  x0 += k0; x1 += k1 + 3u;
  TF_R(17u) TF_R(29u) TF_R(16u) TF_R(24u)
  x0 += k1; x1 += k2 + 4u;
  TF_R(13u) TF_R(15u) TF_R(26u) TF_R(6u)
  x0 += k2; x1 += k0 + 5u;
#undef TF_R
}

__device__ __forceinline__ double fold_pool_w(const float* W, int base, int pos) {
  int iy = pos / 6, ix = pos % 6;
  double w = 0.0;
  for (int dy = 0; dy < 2; ++dy) {
    int ky = iy - dy; if (ky < 0 || ky > 4) continue;
    for (int dx = 0; dx < 2; ++dx) {
      int kx = ix - dx; if (kx < 0 || kx > 4) continue;
      w += (double)W[base + ky * 5 + kx];
    }
  }
  return w;
}

__device__ __forceinline__ uint16_t f2bf(float x) {  // RNE bf16
  uint32_t u = __float_as_uint(x);
  uint32_t r = (u + 0x7fffu + ((u >> 16) & 1u)) >> 16;
  return (uint16_t)r;
}

// f64 masters: W1R [og4][pos36][c3][oj8], W2R [og4][c32][pos36][oj16]
__global__ __launch_bounds__(256) void weff_all(const float* __restrict__ W_in,
                                                const float* __restrict__ W_h1,
                                                double* __restrict__ W1R,
                                                double* __restrict__ W2R) {
  int e = blockIdx.x * 256 + threadIdx.x;
  if (e < 3456) {
    int oj = e & 7, c = (e >> 3) % 3, pos = ((e >> 3) / 3) % 36, og = (e >> 3) / 108;
    int oc = og * 8 + oj;
    W1R[e] = fold_pool_w(W_in, (oc * 3 + c) * 25, pos);
  } else if (e < 3456 + 73728) {
    int e2 = e - 3456;
    int oj = e2 & 15, pos = (e2 >> 4) % 36, c = ((e2 >> 4) / 36) % 32, og = e2 / 18432;
    int oc = og * 16 + oj;
    W2R[e2] = fold_pool_w(W_h1, (oc * 32 + c) * 25, pos);
  }
}

// conv1 MFMA B-frags: WB1[hl2][ks4][nt2][lane64][j8] bf16; k = c*36+pos.
__global__ __launch_bounds__(256) void wprep1b(const float* __restrict__ W_in,
                                               uint16_t* __restrict__ WB1) {
  int e = blockIdx.x * 256 + threadIdx.x;
  if (e >= 16384) return;
  int j = e & 7, lane = (e >> 3) & 63, nt = (e >> 9) & 1, ks = (e >> 10) & 3, hl = e >> 12;
  int k = ks * 32 + (lane >> 4) * 8 + j;
  int oc = nt * 16 + (lane & 15);
  uint16_t val = 0;
  if (k < 108) {
    int c = k / 36, pos = k % 36;
    double w = fold_pool_w(W_in, (oc * 3 + c) * 25, pos);
    uint16_t hi = f2bf((float)w);
    if (hl == 0) val = hi;
    else {
      float hif = __uint_as_float(((uint32_t)hi) << 16);
      val = f2bf((float)(w - (double)hif));
    }
  }
  WB1[e] = val;
}

// conv2 MFMA B-frags: WB2[hl2][pos36][nt4][lane64][j8] bf16 (round-10 layout)
__global__ __launch_bounds__(256) void wprep2(const float* __restrict__ W_h1,
                                              uint16_t* __restrict__ WB) {
  int e = blockIdx.x * 256 + threadIdx.x;
  if (e >= 36 * 4 * 64 * 8) return;
  int j = e & 7, lane = (e >> 3) & 63, nt = (e >> 9) & 3, pos = e >> 11;
  int oc = nt * 16 + (lane & 15);
  int c  = (lane >> 4) * 8 + j;
  double w = fold_pool_w(W_h1, (oc * 32 + c) * 25, pos);
  uint16_t hi = f2bf((float)w);
  float hif = __uint_as_float(((uint32_t)hi) << 16);
  uint16_t lo = f2bf((float)(w - (double)hif));
  WB[e] = hi;
  WB[73728 + e] = lo;
}

// EPS[0..31]: conv1 per-oc flag radius; EPS[32..95]: conv2 per-oc.
__global__ __launch_bounds__(128) void eps_kernel(const double* __restrict__ W1R,
                                                  const double* __restrict__ W2R,
                                                  float* __restrict__ EPS) {
  int oc = blockIdx.x * 128 + threadIdx.x;
  const double u24 = 5.9604644775390625e-08;
  if (oc < 32) {
    int og = oc >> 3, oj = oc & 7;
    double S = 0.0;
    for (int pos = 0; pos < 36; ++pos)
      for (int c = 0; c < 3; ++c) S += fabs(W1R[og * 864 + pos * 24 + c * 8 + oj]);
    EPS[oc] = (float)(S * (108.0 * u24 * 6.0) * 0.25);
  } else if (oc < 96) {
    int o = oc - 32, og = o >> 4, oj = o & 15;
    double S = 0.0;
    for (int c = 0; c < 32; ++c)
      for (int pos = 0; pos < 36; ++pos) S += fabs(W2R[og * 18432 + c * 576 + pos * 16 + oj]);
    EPS[oc] = (float)(S * (1152.0 * u24 * 6.0) * 0.25);
  }
}

// --- spike gen via ballot: rowm[tb][c][32 rows] u32 -----------------------
// wave id = tb*48 + c*16 + rp; lanes = 64 pixels (rows 2rp, 2rp+1).
__global__ __launch_bounds__(256) void gen_spikes(const float* __restrict__ x,
                                                  uint32_t* __restrict__ rowm) {
  int id = blockIdx.x * 4 + (threadIdx.x >> 6);
  int lane = threadIdx.x & 63;
  int rp = id & 15, c = (id >> 4) % 3, tb = id / 48;
  int pix = rp * 64 + lane;
  int b = tb & 63;
  uint32_t i = (uint32_t)((tb * 3 + c) * 1024 + pix);
  uint32_t x0 = 0u, x1 = i;
  threefry2x32(0u, 1u, x0, x1);
  uint32_t bits = x0 ^ x1;
  float u = __uint_as_float((bits >> 9) | 0x3f800000u) - 1.0f;
  float xv = x[(b * 3 + c) * 1024 + pix];
  unsigned long long mask = __ballot(u < 2.0f * xv);
  if (lane == 0) ((unsigned long long*)rowm)[id] = mask;
}

// --- win_prep: per (tb, pixel) pack 108-bit K-window (k=c*36+pos) ---------
__global__ __launch_bounds__(256) void win_prep(const uint32_t* __restrict__ rowm,
                                                uint4* __restrict__ win1) {
  const int tb = blockIdx.x;
  const int tid = threadIdx.x;
  __shared__ uint32_t sR[96];
  if (tid < 96) sR[tid] = rowm[tb * 96 + tid];
  __syncthreads();
  if (tid < 196) {
    int oh = tid / 14, ow = tid % 14;
    uint64_t seg[3];
    #pragma unroll
    for (int c = 0; c < 3; ++c) {
      uint64_t s = 0;
      #pragma unroll
      for (int iy = 0; iy < 6; ++iy)
        s |= (uint64_t)((sR[c * 32 + 2 * oh + iy] >> (2 * ow)) & 0x3fu) << (6 * iy);
      seg[c] = s;
    }
    uint64_t lo = seg[0] | (seg[1] << 36);
    uint64_t hi = (seg[1] >> 28) | (seg[2] << 8);
    uint4 w;
    w.x = (uint32_t)lo; w.y = (uint32_t)(lo >> 32);
    w.z = (uint32_t)hi; w.w = (uint32_t)(hi >> 32);
    win1[tb * 196 + tid] = w;
  }
}

// --- conv1 via MFMA: wave = tb; 13 m-tiles, N=32, K=128(108), hi/lo -------
__global__ __launch_bounds__(256) void conv1_mfma(const uint4* __restrict__ win1,
                                                  const uint16_t* __restrict__ WB1,
                                                  const float* __restrict__ EPS,
                                                  uint32_t* __restrict__ A1w,
                                                  uint32_t* __restrict__ B1w,
                                                  uint32_t* __restrict__ F1w) {
  const int tid = threadIdx.x;
  const int wid = tid >> 6, lane = tid & 63;
  const int tb = blockIdx.x * 4 + wid;    // 0..6399
  const int q = lane >> 4, ln = lane & 15;

  const float eps0 = EPS[ln];
  const float eps1 = EPS[16 + ln];

  bf16x8 bf[2][4][2];
  #pragma unroll
  for (int hl = 0; hl < 2; ++hl)
    #pragma unroll
    for (int ks = 0; ks < 4; ++ks)
      #pragma unroll
      for (int nt = 0; nt < 2; ++nt)
        bf[hl][ks][nt] =
            *(const bf16x8*)(WB1 + ((((hl * 4 + ks) * 2 + nt) * 64 + lane) * 8));

  const int wl = lane;                    // writer identity
  const int qq = wl >> 2, rr = wl & 3;

  for (int mt = 0; mt < 13; ++mt) {
    int p = mt * 16 + ln;
    int pc = p < 196 ? p : 195;           // clamp; garbage rows never stored
    uint4 win = win1[tb * 196 + pc];
    uint32_t wz[4] = {win.x, win.y, win.z, win.w};

    f32x4 acc0 = (f32x4)(0.0f), acc1 = (f32x4)(0.0f);
    #pragma unroll
    for (int ks = 0; ks < 4; ++ks) {
      uint32_t byte = (wz[ks] >> (q * 8)) & 0xffu;
      union { uint32_t u[4]; bf16x8 v; } a;
      #pragma unroll
      for (int i = 0; i < 4; ++i)
        a.u[i] = (((byte >> (2 * i)) & 1u) ? 0x3F80u : 0u) |
                 (((byte >> (2 * i + 1)) & 1u) ? 0x3F800000u : 0u);
      acc0 = __builtin_amdgcn_mfma_f32_16x16x32_bf16(a.v, bf[0][ks][0], acc0, 0, 0, 0);
      acc0 = __builtin_amdgcn_mfma_f32_16x16x32_bf16(a.v, bf[1][ks][0], acc0, 0, 0, 0);
      acc1 = __builtin_amdgcn_mfma_f32_16x16x32_bf16(a.v, bf[0][ks][1], acc1, 0, 0, 0);
      acc1 = __builtin_amdgcn_mfma_f32_16x16x32_bf16(a.v, bf[1][ks][1], acc1, 0, 0, 0);
    }

    // epilogue: ballots (v_cmp -> 64-bit mask). D: col=lane&15, row=q*4+reg.
    unsigned long long bA0[4], bA1[4], bB0[4], bB1[4], bF0[4], bF1[4];
    #pragma unroll
    for (int r = 0; r < 4; ++r) {
      float c0 = acc0[r] * 0.25f;
      float c1 = acc1[r] * 0.25f;
      bA0[r] = __ballot(c0 > 1.0f);
      bB0[r] = __ballot(c0 > 2.0f);
      bF0[r] = __ballot(fabsf(c0 - 1.0f) <= eps0 || fabsf(c0 - 2.0f) <= eps0);
      bA1[r] = __ballot(c1 > 1.0f);
      bB1[r] = __ballot(c1 > 2.0f);
      bF1[r] = __ballot(fabsf(c1 - 1.0f) <= eps1 || fabsf(c1 - 2.0f) <= eps1);
    }

    int pw = mt * 16 + wl;
    if (wl < 16 && pw < 196) {
#define SEL(B) (rr == 0 ? B[0] : rr == 1 ? B[1] : rr == 2 ? B[2] : B[3])
      uint32_t wA = (uint32_t)((SEL(bA0) >> (qq * 16)) & 0xffffull) |
                    ((uint32_t)((SEL(bA1) >> (qq * 16)) & 0xffffull) << 16);
      uint32_t wB = (uint32_t)((SEL(bB0) >> (qq * 16)) & 0xffffull) |
                    ((uint32_t)((SEL(bB1) >> (qq * 16)) & 0xffffull) << 16);
      uint32_t wF = (uint32_t)((SEL(bF0) >> (qq * 16)) & 0xffffull) |
                    ((uint32_t)((SEL(bF1) >> (qq * 16)) & 0xffffull) << 16);
#undef SEL
      uint32_t idx = (uint32_t)(tb * 196 + pw);
      A1w[idx] = wA;
      B1w[idx] = wB;
      F1w[idx] = wF;
    }
  }
}

// --- fixup 1: scan F1, exact f64 recompute from rowm, patch bits ----------
__global__ __launch_bounds__(256) void fix1(const uint32_t* __restrict__ F1w,
                                            const uint32_t* __restrict__ rowm,
                                            const double* __restrict__ W1R,
                                            unsigned char* __restrict__ A1,
                                            unsigned char* __restrict__ B1) {
  int wi = blockIdx.x * 256 + threadIdx.x;
  if (wi >= 1254400) return;
  uint32_t w = F1w[wi];
  if (!w) return;
  for (int k = 0; k < 4; ++k) {
    unsigned fb = (w >> (k * 8)) & 0xffu;
    if (!fb) continue;
    int byteIdx = wi * 4 + k;
    int og = byteIdx & 3, x = byteIdx >> 2;
    int tb = x / 196, p = x % 196;
    int oh = p / 14, ow = p % 14;
    const uint32_t* R = rowm + (size_t)tb * 96;
    unsigned a = A1[byteIdx], bbyte = B1[byteIdx];
    for (int oj = 0; oj < 8; ++oj) {
      if (!((fb >> oj) & 1u)) continue;
      double acc = 0.0;
      for (int iy = 0; iy < 6; ++iy)
        for (int ix = 0; ix < 6; ++ix)
          for (int c = 0; c < 3; ++c) {
            double bd = (double)((R[c * 32 + 2 * oh + iy] >> (2 * ow + ix)) & 1u);
            acc = fma(bd, W1R[og * 864 + (iy * 6 + ix) * 24 + c * 8 + oj], acc);
          }
      float cur = (float)(acc * 0.25);
      unsigned m = 1u << oj;
      a = (cur > 1.0f) ? (a | m) : (a & ~m);
      bbyte = (cur > 2.0f) ? (bbyte | m) : (bbyte & ~m);
    }
    A1[byteIdx] = (unsigned char)a;
    B1[byteIdx] = (unsigned char)bbyte;
  }
}

// --- LIF1 scan: batched register prefetch --------------------------------
__global__ __launch_bounds__(64) void scan1(const uint32_t* __restrict__ A1w,
                                            const uint32_t* __restrict__ B1w,
                                            uint32_t* __restrict__ mask1) {
  int chain = blockIdx.x * 64 + threadIdx.x;
  if (chain >= NB * 196) return;
  int b = chain / 196, p = chain % 196;
  const size_t stride = (size_t)NB * 196;
  size_t base = (size_t)b * 196 + p;
  uint32_t prev = 0;
  #pragma unroll
  for (int seg = 0; seg < 4; ++seg) {
    uint32_t Abuf[25], Bbuf[25];
    size_t sb = base + (size_t)(seg * 25) * stride;
    #pragma unroll
    for (int i = 0; i < 25; ++i) {
      Abuf[i] = A1w[sb + i * stride];
      Bbuf[i] = B1w[sb + i * stride];
    }
    #pragma unroll
    for (int i = 0; i < 25; ++i) {
      uint32_t s = (Abuf[i] & ~prev) | (Bbuf[i] & prev);
      mask1[sb + i * stride] = s;
      prev = s;
    }
  }
}

// --- conv2 via MFMA (round 10, unchanged) ---------------------------------
__global__ __launch_bounds__(256, 2) void conv2_mfma(const uint32_t* __restrict__ mask1,
                                                     const uint16_t* __restrict__ WB,
                                                     const float* __restrict__ EPS,
                                                     unsigned char* __restrict__ A2,
                                                     unsigned char* __restrict__ B2,
                                                     unsigned char* __restrict__ F2) {
  __shared__ uint32_t sM[4 * 196];
  __shared__ float sCur[4][32 * 64];
  __shared__ float sEps[64];
  const int tid = threadIdx.x;
  const int wid = tid >> 6, lane = tid & 63;
  const int tb = blockIdx.x * 4 + wid;

  {
    const uint32_t* src = mask1 + (size_t)tb * 196;
    for (int i = lane; i < 196; i += 64) sM[wid * 196 + i] = src[i];
  }
  if (tid < 64) sEps[tid] = EPS[32 + tid];
  __syncthreads();

  const int q  = lane >> 4;
  const int ln = lane & 15;
  const int p0 = ln;
  const int p1 = 16 + ln;
  const bool v1 = (p1 < 25);
  const int oh0 = p0 / 5, ow0 = p0 % 5;
  const int p1c = v1 ? p1 : 0;
  const int oh1 = p1c / 5, ow1 = p1c % 5;

  f32x4 acc[8];
  #pragma unroll
  for (int i = 0; i < 8; ++i) acc[i] = (f32x4)(0.0f);

  const uint32_t* sMw = &sM[wid * 196];

  for (int iy = 0; iy < 6; ++iy) {
    #pragma unroll
    for (int ix = 0; ix < 6; ++ix) {
      const int pos = iy * 6 + ix;
      uint32_t w0 = sMw[(2 * oh0 + iy) * 14 + 2 * ow0 + ix];
      uint32_t w1 = v1 ? sMw[(2 * oh1 + iy) * 14 + 2 * ow1 + ix] : 0u;
      uint32_t bits0 = (w0 >> (q * 8)) & 0xffu;
      uint32_t bits1 = (w1 >> (q * 8)) & 0xffu;
      union { uint32_t u[4]; bf16x8 v; } a0, a1;
      #pragma unroll
      for (int i = 0; i < 4; ++i) {
        a0.u[i] = (((bits0 >> (2 * i)) & 1u) ? 0x3F80u : 0u) |
                  (((bits0 >> (2 * i + 1)) & 1u) ? 0x3F800000u : 0u);
        a1.u[i] = (((bits1 >> (2 * i)) & 1u) ? 0x3F80u : 0u) |
                  (((bits1 >> (2 * i + 1)) & 1u) ? 0x3F800000u : 0u);
      }
      const uint16_t* bhi_base = WB + (size_t)pos * 2048 + lane * 8;
      const uint16_t* blo_base = bhi_base + 73728;
      #pragma unroll
      for (int nt = 0; nt < 4; ++nt) {
        bf16x8 bhi = *(const bf16x8*)(bhi_base + nt * 512);
        bf16x8 blo = *(const bf16x8*)(blo_base + nt * 512);
        acc[nt] = __builtin_amdgcn_mfma_f32_16x16x32_bf16(a0.v, bhi, acc[nt], 0, 0, 0);
        acc[nt] = __builtin_amdgcn_mfma_f32_16x16x32_bf16(a0.v, blo, acc[nt], 0, 0, 0);
        acc[4 + nt] = __builtin_amdgcn_mfma_f32_16x16x32_bf16(a1.v, bhi, acc[4 + nt], 0, 0, 0);
        acc[4 + nt] = __builtin_amdgcn_mfma_f32_16x16x32_bf16(a1.v, blo, acc[4 + nt], 0, 0, 0);
      }
    }
  }

  float* sc = &sCur[wid][0];
  #pragma unroll
  for (int nt = 0; nt < 4; ++nt) {
    #pragma unroll
    for (int reg = 0; reg < 4; ++reg) {
      sc[(q * 4 + reg) * 64 + nt * 16 + ln]      = acc[nt][reg];
      sc[(16 + q * 4 + reg) * 64 + nt * 16 + ln] = acc[4 + nt][reg];
    }
  }
  const int p  = lane >> 1;
  const int hf = lane & 1;
  if (p < 25) {
    uint32_t aw = 0, bw = 0, fw = 0;
    #pragma unroll
    for (int jo = 0; jo < 32; ++jo) {
      int oc = hf * 32 + jo;
      float cur = sc[p * 64 + oc] * 0.25f;
      float e = sEps[oc];
      uint32_t bit = 1u << jo;
      if (cur > 1.0f) aw |= bit;
      if (cur > 2.0f) bw |= bit;
      if (fabsf(cur - 1.0f) <= e || fabsf(cur - 2.0f) <= e) fw |= bit;
    }
    uint32_t widx = (uint32_t)(tb * 25 + p) * 2 + hf;
    ((uint32_t*)A2)[widx] = aw;
    ((uint32_t*)B2)[widx] = bw;
    ((uint32_t*)F2)[widx] = fw;
  }
}

// --- fixup 2 (unchanged) ---------------------------------------------------
__global__ __launch_bounds__(256) void fix2(const uint32_t* __restrict__ F2w,
                                            const uint32_t* __restrict__ mask1,
                                            const double* __restrict__ W2R,
                                            unsigned char* __restrict__ A2,
                                            unsigned char* __restrict__ B2) {
  int wi = blockIdx.x * 256 + threadIdx.x;
  if (wi >= 320000) return;
  uint32_t w = F2w[wi];
  if (!w) return;
  for (int k = 0; k < 4; ++k) {
    unsigned fb = (w >> (k * 8)) & 0xffu;
    if (!fb) continue;
    int byteIdx = wi * 4 + k;
    int og2 = byteIdx & 7, og = og2 >> 1, h = og2 & 1;
    int x = byteIdx >> 3;
    int tb = x / 25, p = x % 25;
    int oh = p / 5, ow = p % 5;
    const uint32_t* M = mask1 + (size_t)tb * 196;
    unsigned a = A2[byteIdx], bbyte = B2[byteIdx];
    for (int bit = 0; bit < 8; ++bit) {
      if (!((fb >> bit) & 1u)) continue;
      int oj = h * 8 + bit;
      double acc = 0.0;
      for (int c = 0; c < 32; ++c)
        for (int iy = 0; iy < 6; ++iy)
          for (int ix = 0; ix < 6; ++ix) {
            uint32_t mm = M[(2 * oh + iy) * 14 + 2 * ow + ix];
            double bd = (double)((mm >> c) & 1u);
            acc = fma(bd, W2R[og * 18432 + c * 576 + (iy * 6 + ix) * 16 + oj], acc);
          }
      float cur = (float)(acc * 0.25);
      unsigned m = 1u << bit;
      a = (cur > 1.0f) ? (a | m) : (a & ~m);
      bbyte = (cur > 2.0f) ? (bbyte | m) : (bbyte & ~m);
    }
    A2[byteIdx] = (unsigned char)a;
    B2[byteIdx] = (unsigned char)bbyte;
  }
}

// --- LIF2 scan -------------------------------------------------------------
__global__ __launch_bounds__(64) void scan2(const uint64_t* __restrict__ A2q,
                                            const uint64_t* __restrict__ B2q,
                                            uint64_t* __restrict__ mask2) {
  int chain = blockIdx.x * 64 + threadIdx.x;
  if (chain >= NB * 25) return;
  int b = chain / 25, p = chain % 25;
  const size_t stride = (size_t)NB * 25;
  size_t base = (size_t)b * 25 + p;
  uint64_t prev = 0;
  #pragma unroll
  for (int seg = 0; seg < 4; ++seg) {
    uint64_t Abuf[25], Bbuf[25];
    size_t sb = base + (size_t)(seg * 25) * stride;
    #pragma unroll
    for (int i = 0; i < 25; ++i) {
      Abuf[i] = A2q[sb + i * stride];
      Bbuf[i] = B2q[sb + i * stride];
    }
    #pragma unroll
    for (int i = 0; i < 25; ++i) {
      uint64_t s = (Abuf[i] & ~prev) | (Bbuf[i] & prev);
      mask2[sb + i * stride] = s;
      prev = s;
    }
  }
}

// --- FC (unchanged) --------------------------------------------------------
__global__ __launch_bounds__(256) void fc_kernel(const uint64_t* __restrict__ mask2,
                                                 const float* __restrict__ W2,
                                                 float* __restrict__ cur3) {
  int gid = blockIdx.x * 256 + threadIdx.x;
  if (gid >= NSTEPS * NB * 80) return;
  int tb = gid / 80, r = gid % 80;
  int o = r >> 3, s = r & 7;
  const uint64_t* m = mask2 + (size_t)tb * 25;
  const float* w = W2 + o * 1600 + s * 200;

  uint64_t mw[25];
  #pragma unroll
  for (int p = 0; p < 25; ++p) mw[p] = m[p];

  const int oc0 = s * 8;
  double acc0 = 0.0, acc1 = 0.0;
  #pragma unroll
  for (int j = 0; j < 8; ++j) {
    const float* wj = w + j * 25;
    double a = 0.0;
    #pragma unroll
    for (int p = 0; p < 25; ++p) {
      double bd = (double)((mw[p] >> (oc0 + j)) & 1ull);
      a = fma(bd, (double)wj[p], a);
    }
    if (j & 1) acc1 += a; else acc0 += a;
  }
  double acc = acc0 + acc1;
  acc += __shfl_xor(acc, 4);
  acc += __shfl_xor(acc, 2);
  acc += __shfl_xor(acc, 1);
  if (s == 0) cur3[tb * 10 + o] = (float)acc;
}

// --- LIF3 (unchanged) ------------------------------------------------------
__global__ __launch_bounds__(64) void lif3_kernel(const float* __restrict__ cur3,
                                                  float* __restrict__ out) {
  int bo = blockIdx.x * 64 + threadIdx.x;
  if (bo >= NB * 10) return;
  float prev = 0.0f;
  #pragma unroll
  for (int seg = 0; seg < 4; ++seg) {
    float cbuf[25];
    #pragma unroll
    for (int i = 0; i < 25; ++i) cbuf[i] = cur3[(seg * 25 + i) * 640 + bo];
    #pragma unroll
    for (int i = 0; i < 25; ++i) {
      int t = seg * 25 + i;
      float mem = cbuf[i] - prev;
      bool s = mem > 1.0f;
      out[t * 640 + bo] = s ? 1.0f : 0.0f;
      out[NSTEPS * 640 + t * 640 + bo] = mem;
      prev = s ? 1.0f : 0.0f;
    }
  }
}

extern "C" void kernel_launch(void* const* d_in, const int* in_sizes, int n_in,
                              void* d_out, int out_size, void* d_ws, size_t ws_size,
                              hipStream_t stream) {
  const float* x    = (const float*)d_in[0];
  const float* W_in = (const float*)d_in[1];
  const float* W_h1 = (const float*)d_in[2];
  const float* W_h2 = (const float*)d_in[3];
  float* out = (float*)d_out;

  unsigned char* ws = (unsigned char*)d_ws;
  double*        W1R   = (double*)(ws + 0);            //     27,648
  double*        W2R   = (double*)(ws + 27648);        //    589,824
  uint16_t*      WB1   = (uint16_t*)(ws + 617472);     //     32,768
  uint16_t*      WB2   = (uint16_t*)(ws + 650240);     //    294,912
  float*         EPS   = (float*)(ws + 945152);        //        384
  uint32_t*      rowm  = (uint32_t*)(ws + 946176);     //  2,457,600
  uint4*         win1  = (uint4*)(ws + 3403776);       // 20,070,400
  unsigned char* A1    = ws + 23474176;                //  5,017,600
  unsigned char* B1    = ws + 28491776;                //  5,017,600
  unsigned char* F1    = ws + 33509376;                //  5,017,600
  uint32_t*      mask1 = (uint32_t*)(ws + 38526976);   //  5,017,600
  unsigned char* A2    = ws + 43544576;                //  1,280,000
  unsigned char* B2    = ws + 44824576;                //  1,280,000
  unsigned char* F2    = ws + 46104576;                //  1,280,000
  uint64_t*      mask2 = (uint64_t*)(ws + 47384576);   //  1,280,000
  float*         cur3  = (float*)(ws + 48664576);      //    256,000 (end ~49 MB)

  weff_all<<<302, 256, 0, stream>>>(W_in, W_h1, W1R, W2R);
  wprep1b<<<64, 256, 0, stream>>>(W_in, WB1);
  wprep2<<<288, 256, 0, stream>>>(W_h1, WB2);
  eps_kernel<<<1, 128, 0, stream>>>(W1R, W2R, EPS);
  gen_spikes<<<76800, 256, 0, stream>>>(x, rowm);
  win_prep<<<6400, 256, 0, stream>>>(rowm, win1);
  conv1_mfma<<<1600, 256, 0, stream>>>(win1, WB1, EPS,
                                       (uint32_t*)A1, (uint32_t*)B1, (uint32_t*)F1);
  fix1<<<(1254400 + 255) / 256, 256, 0, stream>>>((const uint32_t*)F1, rowm, W1R, A1, B1);
  scan1<<<(NB * 196 + 63) / 64, 64, 0, stream>>>((const uint32_t*)A1,
                                                 (const uint32_t*)B1, mask1);
  conv2_mfma<<<1600, 256, 0, stream>>>(mask1, WB2, EPS, A2, B2, F2);
  fix2<<<(320000 + 255) / 256, 256, 0, stream>>>((const uint32_t*)F2, mask1, W2R, A2, B2);
  scan2<<<(NB * 25 + 63) / 64, 64, 0, stream>>>((const uint64_t*)A2,
                                                (const uint64_t*)B2, mask2);
  fc_kernel<<<(NSTEPS * NB * 80 + 255) / 256, 256, 0, stream>>>(mask2, W_h2, cur3);
  lif3_kernel<<<10, 64, 0, stream>>>(cur3, out);
}

// Round 12
// 404.677 us; speedup vs baseline: 7.7663x; 1.0106x over previous
//
#include <hip/hip_runtime.h>
#include <stdint.h>

// ---------------------------------------------------------------------------
// Conv-SNN, 100 steps, B=64, BETA=0.
// Round 12: conv2_mfma epilogue -> ballot-based (conv1's validated scheme).
//  - deletes the sCur LDS tile (source of 1.2e7 bank conflicts: row stride
//    64 = 0 mod 32 banks on write, 25-way conflicts on readback) and sEps.
//  - LDS 36KB -> 3.1KB, launch_bounds(256,4): occupancy 2 -> 4+ blocks/CU.
//  - A2/B2/F2 word layout unchanged; accumulation loop unchanged -> bits
//    identical after the (unchanged) f64 fixup. All other kernels as r11.
// ---------------------------------------------------------------------------

#define NSTEPS 100
#define NB 64

typedef short bf16x8 __attribute__((ext_vector_type(8)));
typedef float f32x4 __attribute__((ext_vector_type(4)));

__device__ __forceinline__ uint32_t rotl32(uint32_t v, uint32_t r) {
  return (v << r) | (v >> (32u - r));
}

__device__ __forceinline__ void threefry2x32(uint32_t k0, uint32_t k1,
                                             uint32_t& x0, uint32_t& x1) {
  uint32_t k2 = k0 ^ k1 ^ 0x1BD11BDAu;
  x0 += k0; x1 += k1;
#define TF_R(r) { x0 += x1; x1 = rotl32(x1, r); x1 ^= x0; }
  TF_R(13u) TF_R(15u) TF_R(26u) TF_R(6u)
  x0 += k1; x1 += k2 + 1u;
  TF_R(17u) TF_R(29u) TF_R(16u) TF_R(24u)
  x0 += k2; x1 += k0 + 2u;
  TF_R(13u) TF_R(15u) TF_R(26u) TF_R(6u)
  x0 += k0; x1 += k1 + 3u;
  TF_R(17u) TF_R(29u) TF_R(16u) TF_R(24u)
  x0 += k1; x1 += k2 + 4u;
  TF_R(13u) TF_R(15u) TF_R(26u) TF_R(6u)
  x0 += k2; x1 += k0 + 5u;
#undef TF_R
}

__device__ __forceinline__ double fold_pool_w(const float* W, int base, int pos) {
  int iy = pos / 6, ix = pos % 6;
  double w = 0.0;
  for (int dy = 0; dy < 2; ++dy) {
    int ky = iy - dy; if (ky < 0 || ky > 4) continue;
    for (int dx = 0; dx < 2; ++dx) {
      int kx = ix - dx; if (kx < 0 || kx > 4) continue;
      w += (double)W[base + ky * 5 + kx];
    }
  }
  return w;
}

__device__ __forceinline__ uint16_t f2bf(float x) {  // RNE bf16
  uint32_t u = __float_as_uint(x);
  uint32_t r = (u + 0x7fffu + ((u >> 16) & 1u)) >> 16;
  return (uint16_t)r;
}

// f64 masters: W1R [og4][pos36][c3][oj8], W2R [og4][c32][pos36][oj16]
__global__ __launch_bounds__(256) void weff_all(const float* __restrict__ W_in,
                                                const float* __restrict__ W_h1,
                                                double* __restrict__ W1R,
                                                double* __restrict__ W2R) {
  int e = blockIdx.x * 256 + threadIdx.x;
  if (e < 3456) {
    int oj = e & 7, c = (e >> 3) % 3, pos = ((e >> 3) / 3) % 36, og = (e >> 3) / 108;
    int oc = og * 8 + oj;
    W1R[e] = fold_pool_w(W_in, (oc * 3 + c) * 25, pos);
  } else if (e < 3456 + 73728) {
    int e2 = e - 3456;
    int oj = e2 & 15, pos = (e2 >> 4) % 36, c = ((e2 >> 4) / 36) % 32, og = e2 / 18432;
    int oc = og * 16 + oj;
    W2R[e2] = fold_pool_w(W_h1, (oc * 32 + c) * 25, pos);
  }
}

// conv1 MFMA B-frags: WB1[hl2][ks4][nt2][lane64][j8] bf16; k = c*36+pos.
__global__ __launch_bounds__(256) void wprep1b(const float* __restrict__ W_in,
                                               uint16_t* __restrict__ WB1) {
  int e = blockIdx.x * 256 + threadIdx.x;
  if (e >= 16384) return;
  int j = e & 7, lane = (e >> 3) & 63, nt = (e >> 9) & 1, ks = (e >> 10) & 3, hl = e >> 12;
  int k = ks * 32 + (lane >> 4) * 8 + j;
  int oc = nt * 16 + (lane & 15);
  uint16_t val = 0;
  if (k < 108) {
    int c = k / 36, pos = k % 36;
    double w = fold_pool_w(W_in, (oc * 3 + c) * 25, pos);
    uint16_t hi = f2bf((float)w);
    if (hl == 0) val = hi;
    else {
      float hif = __uint_as_float(((uint32_t)hi) << 16);
      val = f2bf((float)(w - (double)hif));
    }
  }
  WB1[e] = val;
}

// conv2 MFMA B-frags: WB2[hl2][pos36][nt4][lane64][j8] bf16
__global__ __launch_bounds__(256) void wprep2(const float* __restrict__ W_h1,
                                              uint16_t* __restrict__ WB) {
  int e = blockIdx.x * 256 + threadIdx.x;
  if (e >= 36 * 4 * 64 * 8) return;
  int j = e & 7, lane = (e >> 3) & 63, nt = (e >> 9) & 3, pos = e >> 11;
  int oc = nt * 16 + (lane & 15);
  int c  = (lane >> 4) * 8 + j;
  double w = fold_pool_w(W_h1, (oc * 32 + c) * 25, pos);
  uint16_t hi = f2bf((float)w);
  float hif = __uint_as_float(((uint32_t)hi) << 16);
  uint16_t lo = f2bf((float)(w - (double)hif));
  WB[e] = hi;
  WB[73728 + e] = lo;
}

// EPS[0..31]: conv1 per-oc flag radius; EPS[32..95]: conv2 per-oc.
__global__ __launch_bounds__(128) void eps_kernel(const double* __restrict__ W1R,
                                                  const double* __restrict__ W2R,
                                                  float* __restrict__ EPS) {
  int oc = blockIdx.x * 128 + threadIdx.x;
  const double u24 = 5.9604644775390625e-08;
  if (oc < 32) {
    int og = oc >> 3, oj = oc & 7;
    double S = 0.0;
    for (int pos = 0; pos < 36; ++pos)
      for (int c = 0; c < 3; ++c) S += fabs(W1R[og * 864 + pos * 24 + c * 8 + oj]);
    EPS[oc] = (float)(S * (108.0 * u24 * 6.0) * 0.25);
  } else if (oc < 96) {
    int o = oc - 32, og = o >> 4, oj = o & 15;
    double S = 0.0;
    for (int c = 0; c < 32; ++c)
      for (int pos = 0; pos < 36; ++pos) S += fabs(W2R[og * 18432 + c * 576 + pos * 16 + oj]);
    EPS[oc] = (float)(S * (1152.0 * u24 * 6.0) * 0.25);
  }
}

// --- spike gen via ballot: rowm[tb][c][32 rows] u32 -----------------------
__global__ __launch_bounds__(256) void gen_spikes(const float* __restrict__ x,
                                                  uint32_t* __restrict__ rowm) {
  int id = blockIdx.x * 4 + (threadIdx.x >> 6);
  int lane = threadIdx.x & 63;
  int rp = id & 15, c = (id >> 4) % 3, tb = id / 48;
  int pix = rp * 64 + lane;
  int b = tb & 63;
  uint32_t i = (uint32_t)((tb * 3 + c) * 1024 + pix);
  uint32_t x0 = 0u, x1 = i;
  threefry2x32(0u, 1u, x0, x1);
  uint32_t bits = x0 ^ x1;
  float u = __uint_as_float((bits >> 9) | 0x3f800000u) - 1.0f;
  float xv = x[(b * 3 + c) * 1024 + pix];
  unsigned long long mask = __ballot(u < 2.0f * xv);
  if (lane == 0) ((unsigned long long*)rowm)[id] = mask;
}

// --- win_prep: per (tb, pixel) pack 108-bit K-window (k=c*36+pos) ---------
__global__ __launch_bounds__(256) void win_prep(const uint32_t* __restrict__ rowm,
                                                uint4* __restrict__ win1) {
  const int tb = blockIdx.x;
  const int tid = threadIdx.x;
  __shared__ uint32_t sR[96];
  if (tid < 96) sR[tid] = rowm[tb * 96 + tid];
  __syncthreads();
  if (tid < 196) {
    int oh = tid / 14, ow = tid % 14;
    uint64_t seg[3];
    #pragma unroll
    for (int c = 0; c < 3; ++c) {
      uint64_t s = 0;
      #pragma unroll
      for (int iy = 0; iy < 6; ++iy)
        s |= (uint64_t)((sR[c * 32 + 2 * oh + iy] >> (2 * ow)) & 0x3fu) << (6 * iy);
      seg[c] = s;
    }
    uint64_t lo = seg[0] | (seg[1] << 36);
    uint64_t hi = (seg[1] >> 28) | (seg[2] << 8);
    uint4 w;
    w.x = (uint32_t)lo; w.y = (uint32_t)(lo >> 32);
    w.z = (uint32_t)hi; w.w = (uint32_t)(hi >> 32);
    win1[tb * 196 + tid] = w;
  }
}

// --- conv1 via MFMA (round 11, unchanged) ---------------------------------
__global__ __launch_bounds__(256) void conv1_mfma(const uint4* __restrict__ win1,
                                                  const uint16_t* __restrict__ WB1,
                                                  const float* __restrict__ EPS,
                                                  uint32_t* __restrict__ A1w,
                                                  uint32_t* __restrict__ B1w,
                                                  uint32_t* __restrict__ F1w) {
  const int tid = threadIdx.x;
  const int wid = tid >> 6, lane = tid & 63;
  const int tb = blockIdx.x * 4 + wid;
  const int q = lane >> 4, ln = lane & 15;

  const float eps0 = EPS[ln];
  const float eps1 = EPS[16 + ln];

  bf16x8 bf[2][4][2];
  #pragma unroll
  for (int hl = 0; hl < 2; ++hl)
    #pragma unroll
    for (int ks = 0; ks < 4; ++ks)
      #pragma unroll
      for (int nt = 0; nt < 2; ++nt)
        bf[hl][ks][nt] =
            *(const bf16x8*)(WB1 + ((((hl * 4 + ks) * 2 + nt) * 64 + lane) * 8));

  const int wl = lane;
  const int qq = wl >> 2, rr = wl & 3;

  for (int mt = 0; mt < 13; ++mt) {
    int p = mt * 16 + ln;
    int pc = p < 196 ? p : 195;
    uint4 win = win1[tb * 196 + pc];
    uint32_t wz[4] = {win.x, win.y, win.z, win.w};

    f32x4 acc0 = (f32x4)(0.0f), acc1 = (f32x4)(0.0f);
    #pragma unroll
    for (int ks = 0; ks < 4; ++ks) {
      uint32_t byte = (wz[ks] >> (q * 8)) & 0xffu;
      union { uint32_t u[4]; bf16x8 v; } a;
      #pragma unroll
      for (int i = 0; i < 4; ++i)
        a.u[i] = (((byte >> (2 * i)) & 1u) ? 0x3F80u : 0u) |
                 (((byte >> (2 * i + 1)) & 1u) ? 0x3F800000u : 0u);
      acc0 = __builtin_amdgcn_mfma_f32_16x16x32_bf16(a.v, bf[0][ks][0], acc0, 0, 0, 0);
      acc0 = __builtin_amdgcn_mfma_f32_16x16x32_bf16(a.v, bf[1][ks][0], acc0, 0, 0, 0);
      acc1 = __builtin_amdgcn_mfma_f32_16x16x32_bf16(a.v, bf[0][ks][1], acc1, 0, 0, 0);
      acc1 = __builtin_amdgcn_mfma_f32_16x16x32_bf16(a.v, bf[1][ks][1], acc1, 0, 0, 0);
    }

    unsigned long long bA0[4], bA1[4], bB0[4], bB1[4], bF0[4], bF1[4];
    #pragma unroll
    for (int r = 0; r < 4; ++r) {
      float c0 = acc0[r] * 0.25f;
      float c1 = acc1[r] * 0.25f;
      bA0[r] = __ballot(c0 > 1.0f);
      bB0[r] = __ballot(c0 > 2.0f);
      bF0[r] = __ballot(fabsf(c0 - 1.0f) <= eps0 || fabsf(c0 - 2.0f) <= eps0);
      bA1[r] = __ballot(c1 > 1.0f);
      bB1[r] = __ballot(c1 > 2.0f);
      bF1[r] = __ballot(fabsf(c1 - 1.0f) <= eps1 || fabsf(c1 - 2.0f) <= eps1);
    }

    int pw = mt * 16 + wl;
    if (wl < 16 && pw < 196) {
#define SEL(B) (rr == 0 ? B[0] : rr == 1 ? B[1] : rr == 2 ? B[2] : B[3])
      uint32_t wA = (uint32_t)((SEL(bA0) >> (qq * 16)) & 0xffffull) |
                    ((uint32_t)((SEL(bA1) >> (qq * 16)) & 0xffffull) << 16);
      uint32_t wB = (uint32_t)((SEL(bB0) >> (qq * 16)) & 0xffffull) |
                    ((uint32_t)((SEL(bB1) >> (qq * 16)) & 0xffffull) << 16);
      uint32_t wF = (uint32_t)((SEL(bF0) >> (qq * 16)) & 0xffffull) |
                    ((uint32_t)((SEL(bF1) >> (qq * 16)) & 0xffffull) << 16);
#undef SEL
      uint32_t idx = (uint32_t)(tb * 196 + pw);
      A1w[idx] = wA;
      B1w[idx] = wB;
      F1w[idx] = wF;
    }
  }
}

// --- fixup 1 (unchanged) ---------------------------------------------------
__global__ __launch_bounds__(256) void fix1(const uint32_t* __restrict__ F1w,
                                            const uint32_t* __restrict__ rowm,
                                            const double* __restrict__ W1R,
                                            unsigned char* __restrict__ A1,
                                            unsigned char* __restrict__ B1) {
  int wi = blockIdx.x * 256 + threadIdx.x;
  if (wi >= 1254400) return;
  uint32_t w = F1w[wi];
  if (!w) return;
  for (int k = 0; k < 4; ++k) {
    unsigned fb = (w >> (k * 8)) & 0xffu;
    if (!fb) continue;
    int byteIdx = wi * 4 + k;
    int og = byteIdx & 3, x = byteIdx >> 2;
    int tb = x / 196, p = x % 196;
    int oh = p / 14, ow = p % 14;
    const uint32_t* R = rowm + (size_t)tb * 96;
    unsigned a = A1[byteIdx], bbyte = B1[byteIdx];
    for (int oj = 0; oj < 8; ++oj) {
      if (!((fb >> oj) & 1u)) continue;
      double acc = 0.0;
      for (int iy = 0; iy < 6; ++iy)
        for (int ix = 0; ix < 6; ++ix)
          for (int c = 0; c < 3; ++c) {
            double bd = (double)((R[c * 32 + 2 * oh + iy] >> (2 * ow + ix)) & 1u);
            acc = fma(bd, W1R[og * 864 + (iy * 6 + ix) * 24 + c * 8 + oj], acc);
          }
      float cur = (float)(acc * 0.25);
      unsigned m = 1u << oj;
      a = (cur > 1.0f) ? (a | m) : (a & ~m);
      bbyte = (cur > 2.0f) ? (bbyte | m) : (bbyte & ~m);
    }
    A1[byteIdx] = (unsigned char)a;
    B1[byteIdx] = (unsigned char)bbyte;
  }
}

// --- LIF1 scan (unchanged) -------------------------------------------------
__global__ __launch_bounds__(64) void scan1(const uint32_t* __restrict__ A1w,
                                            const uint32_t* __restrict__ B1w,
                                            uint32_t* __restrict__ mask1) {
  int chain = blockIdx.x * 64 + threadIdx.x;
  if (chain >= NB * 196) return;
  int b = chain / 196, p = chain % 196;
  const size_t stride = (size_t)NB * 196;
  size_t base = (size_t)b * 196 + p;
  uint32_t prev = 0;
  #pragma unroll
  for (int seg = 0; seg < 4; ++seg) {
    uint32_t Abuf[25], Bbuf[25];
    size_t sb = base + (size_t)(seg * 25) * stride;
    #pragma unroll
    for (int i = 0; i < 25; ++i) {
      Abuf[i] = A1w[sb + i * stride];
      Bbuf[i] = B1w[sb + i * stride];
    }
    #pragma unroll
    for (int i = 0; i < 25; ++i) {
      uint32_t s = (Abuf[i] & ~prev) | (Bbuf[i] & prev);
      mask1[sb + i * stride] = s;
      prev = s;
    }
  }
}

// --- conv2 via MFMA, ballot epilogue (no sCur LDS) ------------------------
__global__ __launch_bounds__(256, 4) void conv2_mfma(const uint32_t* __restrict__ mask1,
                                                     const uint16_t* __restrict__ WB,
                                                     const float* __restrict__ EPS,
                                                     uint32_t* __restrict__ A2w,
                                                     uint32_t* __restrict__ B2w,
                                                     uint32_t* __restrict__ F2w) {
  __shared__ uint32_t sM[4 * 196];
  const int tid = threadIdx.x;
  const int wid = tid >> 6, lane = tid & 63;
  const int tb = blockIdx.x * 4 + wid;

  {
    const uint32_t* src = mask1 + (size_t)tb * 196;
    for (int i = lane; i < 196; i += 64) sM[wid * 196 + i] = src[i];
  }
  __syncthreads();

  const int q  = lane >> 4;
  const int ln = lane & 15;
  float epsv[4];
  #pragma unroll
  for (int nt = 0; nt < 4; ++nt) epsv[nt] = EPS[32 + nt * 16 + ln];

  const int p0 = ln;
  const int p1 = 16 + ln;
  const bool v1 = (p1 < 25);
  const int oh0 = p0 / 5, ow0 = p0 % 5;
  const int p1c = v1 ? p1 : 0;
  const int oh1 = p1c / 5, ow1 = p1c % 5;

  f32x4 acc[8];
  #pragma unroll
  for (int i = 0; i < 8; ++i) acc[i] = (f32x4)(0.0f);

  const uint32_t* sMw = &sM[wid * 196];

  for (int iy = 0; iy < 6; ++iy) {
    #pragma unroll
    for (int ix = 0; ix < 6; ++ix) {
      const int pos = iy * 6 + ix;
      uint32_t w0 = sMw[(2 * oh0 + iy) * 14 + 2 * ow0 + ix];
      uint32_t w1 = v1 ? sMw[(2 * oh1 + iy) * 14 + 2 * ow1 + ix] : 0u;
      uint32_t bits0 = (w0 >> (q * 8)) & 0xffu;
      uint32_t bits1 = (w1 >> (q * 8)) & 0xffu;
      union { uint32_t u[4]; bf16x8 v; } a0, a1;
      #pragma unroll
      for (int i = 0; i < 4; ++i) {
        a0.u[i] = (((bits0 >> (2 * i)) & 1u) ? 0x3F80u : 0u) |
                  (((bits0 >> (2 * i + 1)) & 1u) ? 0x3F800000u : 0u);
        a1.u[i] = (((bits1 >> (2 * i)) & 1u) ? 0x3F80u : 0u) |
                  (((bits1 >> (2 * i + 1)) & 1u) ? 0x3F800000u : 0u);
      }
      const uint16_t* bhi_base = WB + (size_t)pos * 2048 + lane * 8;
      const uint16_t* blo_base = bhi_base + 73728;
      #pragma unroll
      for (int nt = 0; nt < 4; ++nt) {
        bf16x8 bhi = *(const bf16x8*)(bhi_base + nt * 512);
        bf16x8 blo = *(const bf16x8*)(blo_base + nt * 512);
        acc[nt] = __builtin_amdgcn_mfma_f32_16x16x32_bf16(a0.v, bhi, acc[nt], 0, 0, 0);
        acc[nt] = __builtin_amdgcn_mfma_f32_16x16x32_bf16(a0.v, blo, acc[nt], 0, 0, 0);
        acc[4 + nt] = __builtin_amdgcn_mfma_f32_16x16x32_bf16(a1.v, bhi, acc[4 + nt], 0, 0, 0);
        acc[4 + nt] = __builtin_amdgcn_mfma_f32_16x16x32_bf16(a1.v, blo, acc[4 + nt], 0, 0, 0);
      }
    }
  }

  // Ballot epilogue. D layout per tile: row = q*4+reg (+16 for tile 1),
  // col = nt*16+ln. Writer lane w<50 owns word (p=w>>1, hf=w&1).
  const int w = lane;
  const int pw = w >> 1, hfw = w & 1;
  #pragma unroll
  for (int mt2 = 0; mt2 < 2; ++mt2) {
    const int pt = pw - mt2 * 16;
    const bool wvalid = (w < 50) && (pt >= 0) && (pt < 16) && (pw < 25);
    const int qw = (pt & 15) >> 2, rw = pt & 3;
    uint32_t wA = 0, wB = 0, wF = 0;
    #pragma unroll
    for (int nt = 0; nt < 4; ++nt) {
      unsigned long long bA[4], bB[4], bF[4];
      #pragma unroll
      for (int reg = 0; reg < 4; ++reg) {
        float c = acc[mt2 * 4 + nt][reg] * 0.25f;
        float e = epsv[nt];
        bA[reg] = __ballot(c > 1.0f);
        bB[reg] = __ballot(c > 2.0f);
        bF[reg] = __ballot(fabsf(c - 1.0f) <= e || fabsf(c - 2.0f) <= e);
      }
      if (wvalid && (nt >> 1) == hfw) {
        const int sh = (nt & 1) * 16;
#define SEL(B) (rw == 0 ? B[0] : rw == 1 ? B[1] : rw == 2 ? B[2] : B[3])
        wA |= (uint32_t)((SEL(bA) >> (qw * 16)) & 0xffffull) << sh;
        wB |= (uint32_t)((SEL(bB) >> (qw * 16)) & 0xffffull) << sh;
        wF |= (uint32_t)((SEL(bF) >> (qw * 16)) & 0xffffull) << sh;
#undef SEL
      }
    }
    if (wvalid) {
      uint32_t idx = (uint32_t)(tb * 25 + pw) * 2 + hfw;
      A2w[idx] = wA;
      B2w[idx] = wB;
      F2w[idx] = wF;
    }
  }
}

// --- fixup 2 (unchanged) ---------------------------------------------------
__global__ __launch_bounds__(256) void fix2(const uint32_t* __restrict__ F2w,
                                            const uint32_t* __restrict__ mask1,
                                            const double* __restrict__ W2R,
                                            unsigned char* __restrict__ A2,
                                            unsigned char* __restrict__ B2) {
  int wi = blockIdx.x * 256 + threadIdx.x;
  if (wi >= 320000) return;
  uint32_t w = F2w[wi];
  if (!w) return;
  for (int k = 0; k < 4; ++k) {
    unsigned fb = (w >> (k * 8)) & 0xffu;
    if (!fb) continue;
    int byteIdx = wi * 4 + k;
    int og2 = byteIdx & 7, og = og2 >> 1, h = og2 & 1;
    int x = byteIdx >> 3;
    int tb = x / 25, p = x % 25;
    int oh = p / 5, ow = p % 5;
    const uint32_t* M = mask1 + (size_t)tb * 196;
    unsigned a = A2[byteIdx], bbyte = B2[byteIdx];
    for (int bit = 0; bit < 8; ++bit) {
      if (!((fb >> bit) & 1u)) continue;
      int oj = h * 8 + bit;
      double acc = 0.0;
      for (int c = 0; c < 32; ++c)
        for (int iy = 0; iy < 6; ++iy)
          for (int ix = 0; ix < 6; ++ix) {
            uint32_t mm = M[(2 * oh + iy) * 14 + 2 * ow + ix];
            double bd = (double)((mm >> c) & 1u);
            acc = fma(bd, W2R[og * 18432 + c * 576 + (iy * 6 + ix) * 16 + oj], acc);
          }
      float cur = (float)(acc * 0.25);
      unsigned m = 1u << bit;
      a = (cur > 1.0f) ? (a | m) : (a & ~m);
      bbyte = (cur > 2.0f) ? (bbyte | m) : (bbyte & ~m);
    }
    A2[byteIdx] = (unsigned char)a;
    B2[byteIdx] = (unsigned char)bbyte;
  }
}

// --- LIF2 scan (unchanged) -------------------------------------------------
__global__ __launch_bounds__(64) void scan2(const uint64_t* __restrict__ A2q,
                                            const uint64_t* __restrict__ B2q,
                                            uint64_t* __restrict__ mask2) {
  int chain = blockIdx.x * 64 + threadIdx.x;
  if (chain >= NB * 25) return;
  int b = chain / 25, p = chain % 25;
  const size_t stride = (size_t)NB * 25;
  size_t base = (size_t)b * 25 + p;
  uint64_t prev = 0;
  #pragma unroll
  for (int seg = 0; seg < 4; ++seg) {
    uint64_t Abuf[25], Bbuf[25];
    size_t sb = base + (size_t)(seg * 25) * stride;
    #pragma unroll
    for (int i = 0; i < 25; ++i) {
      Abuf[i] = A2q[sb + i * stride];
      Bbuf[i] = B2q[sb + i * stride];
    }
    #pragma unroll
    for (int i = 0; i < 25; ++i) {
      uint64_t s = (Abuf[i] & ~prev) | (Bbuf[i] & prev);
      mask2[sb + i * stride] = s;
      prev = s;
    }
  }
}

// --- FC (unchanged) --------------------------------------------------------
__global__ __launch_bounds__(256) void fc_kernel(const uint64_t* __restrict__ mask2,
                                                 const float* __restrict__ W2,
                                                 float* __restrict__ cur3) {
  int gid = blockIdx.x * 256 + threadIdx.x;
  if (gid >= NSTEPS * NB * 80) return;
  int tb = gid / 80, r = gid % 80;
  int o = r >> 3, s = r & 7;
  const uint64_t* m = mask2 + (size_t)tb * 25;
  const float* w = W2 + o * 1600 + s * 200;

  uint64_t mw[25];
  #pragma unroll
  for (int p = 0; p < 25; ++p) mw[p] = m[p];

  const int oc0 = s * 8;
  double acc0 = 0.0, acc1 = 0.0;
  #pragma unroll
  for (int j = 0; j < 8; ++j) {
    const float* wj = w + j * 25;
    double a = 0.0;
    #pragma unroll
    for (int p = 0; p < 25; ++p) {
      double bd = (double)((mw[p] >> (oc0 + j)) & 1ull);
      a = fma(bd, (double)wj[p], a);
    }
    if (j & 1) acc1 += a; else acc0 += a;
  }
  double acc = acc0 + acc1;
  acc += __shfl_xor(acc, 4);
  acc += __shfl_xor(acc, 2);
  acc += __shfl_xor(acc, 1);
  if (s == 0) cur3[tb * 10 + o] = (float)acc;
}

// --- LIF3 (unchanged) ------------------------------------------------------
__global__ __launch_bounds__(64) void lif3_kernel(const float* __restrict__ cur3,
                                                  float* __restrict__ out) {
  int bo = blockIdx.x * 64 + threadIdx.x;
  if (bo >= NB * 10) return;
  float prev = 0.0f;
  #pragma unroll
  for (int seg = 0; seg < 4; ++seg) {
    float cbuf[25];
    #pragma unroll
    for (int i = 0; i < 25; ++i) cbuf[i] = cur3[(seg * 25 + i) * 640 + bo];
    #pragma unroll
    for (int i = 0; i < 25; ++i) {
      int t = seg * 25 + i;
      float mem = cbuf[i] - prev;
      bool s = mem > 1.0f;
      out[t * 640 + bo] = s ? 1.0f : 0.0f;
      out[NSTEPS * 640 + t * 640 + bo] = mem;
      prev = s ? 1.0f : 0.0f;
    }
  }
}

extern "C" void kernel_launch(void* const* d_in, const int* in_sizes, int n_in,
                              void* d_out, int out_size, void* d_ws, size_t ws_size,
                              hipStream_t stream) {
  const float* x    = (const float*)d_in[0];
  const float* W_in = (const float*)d_in[1];
  const float* W_h1 = (const float*)d_in[2];
  const float* W_h2 = (const float*)d_in[3];
  float* out = (float*)d_out;

  unsigned char* ws = (unsigned char*)d_ws;
  double*        W1R   = (double*)(ws + 0);            //     27,648
  double*        W2R   = (double*)(ws + 27648);        //    589,824
  uint16_t*      WB1   = (uint16_t*)(ws + 617472);     //     32,768
  uint16_t*      WB2   = (uint16_t*)(ws + 650240);     //    294,912
  float*         EPS   = (float*)(ws + 945152);        //        384
  uint32_t*      rowm  = (uint32_t*)(ws + 946176);     //  2,457,600
  uint4*         win1  = (uint4*)(ws + 3403776);       // 20,070,400
  unsigned char* A1    = ws + 23474176;                //  5,017,600
  unsigned char* B1    = ws + 28491776;                //  5,017,600
  unsigned char* F1    = ws + 33509376;                //  5,017,600
  uint32_t*      mask1 = (uint32_t*)(ws + 38526976);   //  5,017,600
  unsigned char* A2    = ws + 43544576;                //  1,280,000
  unsigned char* B2    = ws + 44824576;                //  1,280,000
  unsigned char* F2    = ws + 46104576;                //  1,280,000
  uint64_t*      mask2 = (uint64_t*)(ws + 47384576);   //  1,280,000
  float*         cur3  = (float*)(ws + 48664576);      //    256,000 (end ~49 MB)

  weff_all<<<302, 256, 0, stream>>>(W_in, W_h1, W1R, W2R);
  wprep1b<<<64, 256, 0, stream>>>(W_in, WB1);
  wprep2<<<288, 256, 0, stream>>>(W_h1, WB2);
  eps_kernel<<<1, 128, 0, stream>>>(W1R, W2R, EPS);
  gen_spikes<<<76800, 256, 0, stream>>>(x, rowm);
  win_prep<<<6400, 256, 0, stream>>>(rowm, win1);
  conv1_mfma<<<1600, 256, 0, stream>>>(win1, WB1, EPS,
                                       (uint32_t*)A1, (uint32_t*)B1, (uint32_t*)F1);
  fix1<<<(1254400 + 255) / 256, 256, 0, stream>>>((const uint32_t*)F1, rowm, W1R, A1, B1);
  scan1<<<(NB * 196 + 63) / 64, 64, 0, stream>>>((const uint32_t*)A1,
                                                 (const uint32_t*)B1, mask1);
  conv2_mfma<<<1600, 256, 0, stream>>>(mask1, WB2, EPS,
                                       (uint32_t*)A2, (uint32_t*)B2, (uint32_t*)F2);
  fix2<<<(320000 + 255) / 256, 256, 0, stream>>>((const uint32_t*)F2, mask1, W2R, A2, B2);
  scan2<<<(NB * 25 + 63) / 64, 64, 0, stream>>>((const uint64_t*)A2,
                                                (const uint64_t*)B2, mask2);
  fc_kernel<<<(NSTEPS * NB * 80 + 255) / 256, 256, 0, stream>>>(mask2, W_h2, cur3);
  lif3_kernel<<<10, 64, 0, stream>>>(cur3, out);
}